// Round 18
// baseline (132.756 us; speedup 1.0000x reference)
//
#include <hip/hip_runtime.h>

typedef unsigned short u16;
typedef unsigned int u32;
typedef __bf16 bf16x8 __attribute__((ext_vector_type(8)));
typedef float f32x4 __attribute__((ext_vector_type(4)));
typedef float f32x16 __attribute__((ext_vector_type(16)));
typedef u16 u16x8 __attribute__((ext_vector_type(8)));
typedef u32 u32x2 __attribute__((ext_vector_type(2)));
typedef u32 u32x4 __attribute__((ext_vector_type(4)));

#define MFMA16(a, b, c) __builtin_amdgcn_mfma_f32_16x16x32_bf16((a), (b), (c), 0, 0, 0)
#define MFMA32(a, b, c) __builtin_amdgcn_mfma_f32_32x32x16_bf16((a), (b), (c), 0, 0, 0)

__device__ __forceinline__ u16 f2bf(float f) {
    unsigned int u = __float_as_uint(f);
    u = (u + 0x7FFF + ((u >> 16) & 1)) >> 16;
    return (u16)u;
}

__device__ __forceinline__ float bf2f(u16 v) {
    return __uint_as_float(((u32)v) << 16);
}

__device__ __forceinline__ u32 cvtpk(float a, float b) {
    u32 d;
    asm("v_cvt_pk_bf16_f32 %0, %1, %2" : "=v"(d) : "v"(a), "v"(b));
    return d;
}

__device__ __forceinline__ void gld_lds16(const u16* g, u16* l) {
    __builtin_amdgcn_global_load_lds(
        (const __attribute__((address_space(1))) unsigned int*)g,
        (__attribute__((address_space(3))) unsigned int*)l, 16, 0, 0);
}

// ---------------- fp32 -> bf16 cast, two tensors in one dispatch ----------------
__global__ __launch_bounds__(256) void cvt2_bf16(const float* __restrict__ in1,
                                                 u16* __restrict__ out1, int n41,
                                                 const float* __restrict__ in2,
                                                 u16* __restrict__ out2, int n42) {
    int idx = blockIdx.x * blockDim.x + threadIdx.x;
    int stride = gridDim.x * blockDim.x;
    for (int i = idx; i < n41; i += stride) {
        float4 v = reinterpret_cast<const float4*>(in1)[i];
        ushort4 o;
        o.x = f2bf(v.x); o.y = f2bf(v.y); o.z = f2bf(v.z); o.w = f2bf(v.w);
        reinterpret_cast<ushort4*>(out1)[i] = o;
    }
    for (int i = idx; i < n42; i += stride) {
        float4 v = reinterpret_cast<const float4*>(in2)[i];
        ushort4 o;
        o.x = f2bf(v.x); o.y = f2bf(v.y); o.z = f2bf(v.z); o.w = f2bf(v.w);
        reinterpret_cast<ushort4*>(out2)[i] = o;
    }
}

// ---------------- partial-sum reduce: o = a + b ----------------
__global__ __launch_bounds__(256) void reduce_add(const float4* __restrict__ a,
                                                  const float4* __restrict__ b,
                                                  float4* __restrict__ o, int n4) {
    int idx = blockIdx.x * blockDim.x + threadIdx.x;
    int stride = gridDim.x * blockDim.x;
    for (int i = idx; i < n4; i += stride) {
        float4 va = a[i], vb = b[i];
        float4 vo = {va.x + vb.x, va.y + vb.y, va.z + vb.z, va.w + vb.w};
        o[i] = vo;
    }
}

// ---- bf16 GEMM-256: 256x256 tile, 8 waves (128x64 each, acc[8][4]), depth-3
// counted-vmcnt pipeline, T2 swizzle (r11 pattern), 2D XCD rects. bf16 output.
// Grid: (tiles, SPLITK). 96KB LDS -> 1 block/CU; 192 blocks = ONE round.
template <int SPLITK, int RM, int RN, int XN>
__global__ __launch_bounds__(512) void gemm_bt256(const u16* __restrict__ A,
                                                  const u16* __restrict__ B,
                                                  u16* __restrict__ C,
                                                  int M, int N, int K) {
    __shared__ __align__(16) u16 As[3][256 * 32];   // 3 x 16KB
    __shared__ __align__(16) u16 Bs[3][256 * 32];   // 3 x 16KB (96KB total)

    int bid = blockIdx.x;
    int xcd = bid & 7;
    int r = bid >> 3;
    int tm = (xcd / XN) * RM + (r / RN);
    int tn = (xcd % XN) * RN + (r % RN);
    int m0 = tm << 8, n0 = tn << 8;               // tile = 256 x 256

    int Ks = K / SPLITK;
    int kbase = blockIdx.y * Ks;

    int t = threadIdx.x;
    int w = t >> 6, l = t & 63, lrow = l & 15, lhi = l >> 4;
    int wr = w >> 2, wc = w & 3;                  // 2 x 4 wave grid, 128x64 each

    int rowS = t >> 2;                            // staging row 0..127 (+128 2nd half)
    int col0 = (((t & 3) ^ ((t >> 3) & 3)) << 3); // pre-swizzled source chunk

    const u16* Ag = A + (size_t)m0 * K + kbase;
    const u16* Bg = B + (size_t)n0 * K + kbase;

    auto stage = [&](int sbuf, int kt) {
        int k0 = kt << 5;
        gld_lds16(Ag + (size_t)rowS * K + k0 + col0, &As[sbuf][t * 8]);
        gld_lds16(Ag + (size_t)(rowS + 128) * K + k0 + col0, &As[sbuf][t * 8 + 4096]);
        gld_lds16(Bg + (size_t)rowS * K + k0 + col0, &Bs[sbuf][t * 8]);
        gld_lds16(Bg + (size_t)(rowS + 128) * K + k0 + col0, &Bs[sbuf][t * 8 + 4096]);
    };

    f32x4 acc[8][4] = {};
    int NT = Ks >> 5;                             // 32 at SPLITK=2
    stage(0, 0); stage(1, 1); stage(2, 2);
    asm volatile("s_waitcnt vmcnt(8)" ::: "memory");   // tile 0 landed
    asm volatile("s_barrier" ::: "memory");
    int cur = 0;
    for (int kt = 0; kt < NT; ++kt) {
        bf16x8 af[8], bfr[4];
#pragma unroll
        for (int i = 0; i < 8; ++i) {
            int row = wr * 128 + i * 16 + lrow;
            af[i] = *(const bf16x8*)&As[cur][row * 32 + ((lhi ^ ((row >> 1) & 3)) << 3)];
        }
#pragma unroll
        for (int j = 0; j < 4; ++j) {
            int row = wc * 64 + j * 16 + lrow;
            bfr[j] = *(const bf16x8*)&Bs[cur][row * 32 + ((lhi ^ ((row >> 1) & 3)) << 3)];
        }
        asm volatile("s_waitcnt lgkmcnt(0)" ::: "memory");
        __builtin_amdgcn_sched_barrier(0);
        asm volatile("s_barrier" ::: "memory");   // all waves done reading cur
        if (kt + 3 < NT) stage(cur, kt + 3);
#pragma unroll
        for (int i = 0; i < 8; ++i)
#pragma unroll
            for (int j = 0; j < 4; ++j)
                acc[i][j] = MFMA16(af[i], bfr[j], acc[i][j]);
        if (kt + 1 < NT) {
            if (kt + 3 < NT)      asm volatile("s_waitcnt vmcnt(8)" ::: "memory");
            else if (kt + 2 < NT) asm volatile("s_waitcnt vmcnt(4)" ::: "memory");
            else                  asm volatile("s_waitcnt vmcnt(0)" ::: "memory");
            asm volatile("s_barrier" ::: "memory");
        }
        cur = (cur == 2) ? 0 : cur + 1;
    }
#pragma unroll
    for (int i = 0; i < 8; ++i) {
#pragma unroll
        for (int j = 0; j < 4; ++j) {
            int crow = m0 + wr * 128 + i * 16 + lhi * 4;
            int ccol = n0 + wc * 64 + j * 16 + lrow;
            u16* cp = C + (size_t)blockIdx.y * ((size_t)M * N) + (size_t)crow * N + ccol;
#pragma unroll
            for (int r2 = 0; r2 < 4; ++r2) cp[(size_t)r2 * N] = f2bf(acc[i][j][r2]);
        }
    }
}

// ---- bf16 GEMM: 128x256 tile, 8 waves, depth-3 pipeline, T2 swizzle, XCD rects ----
template <int SPLITK, int RM, int RN, int XN, bool OBF16>
__global__ __launch_bounds__(512) void gemm_bt(const u16* __restrict__ A,
                                               const u16* __restrict__ B,
                                               void* __restrict__ Cv,
                                               int M, int N, int K) {
    __shared__ __align__(16) u16 As[3][128 * 32];
    __shared__ __align__(16) u16 Bs[3][256 * 32];

    int bid = blockIdx.x;
    int xcd = bid & 7;
    int r = bid >> 3;
    int tm = (xcd / XN) * RM + (r / RN);
    int tn = (xcd % XN) * RN + (r % RN);
    int m0 = tm << 7, n0 = tn << 8;

    int Ks = K / SPLITK;
    int kbase = blockIdx.y * Ks;

    int t = threadIdx.x;
    int w = t >> 6, l = t & 63, lrow = l & 15, lhi = l >> 4;
    int wr = w >> 2, wc = w & 3;

    int rowA = t >> 2;
    int col0 = (((t & 3) ^ ((t >> 3) & 3)) << 3);

    const u16* Ag = A + (size_t)m0 * K + kbase;
    const u16* Bg = B + (size_t)n0 * K + kbase;

    auto stage = [&](int sbuf, int kt) {
        int k0 = kt << 5;
        gld_lds16(Ag + (size_t)rowA * K + k0 + col0, &As[sbuf][t * 8]);
        gld_lds16(Bg + (size_t)rowA * K + k0 + col0, &Bs[sbuf][t * 8]);
        gld_lds16(Bg + (size_t)(rowA + 128) * K + k0 + col0, &Bs[sbuf][t * 8 + 4096]);
    };

    f32x4 acc[4][4] = {};
    int NT = Ks >> 5;
    stage(0, 0); stage(1, 1); stage(2, 2);
    asm volatile("s_waitcnt vmcnt(6)" ::: "memory");
    asm volatile("s_barrier" ::: "memory");
    int cur = 0;
    for (int kt = 0; kt < NT; ++kt) {
        bf16x8 af[4], bfr[4];
#pragma unroll
        for (int i = 0; i < 4; ++i) {
            int row = wr * 64 + i * 16 + lrow;
            af[i] = *(const bf16x8*)&As[cur][row * 32 + ((lhi ^ ((row >> 1) & 3)) << 3)];
        }
#pragma unroll
        for (int j = 0; j < 4; ++j) {
            int row = wc * 64 + j * 16 + lrow;
            bfr[j] = *(const bf16x8*)&Bs[cur][row * 32 + ((lhi ^ ((row >> 1) & 3)) << 3)];
        }
        asm volatile("s_waitcnt lgkmcnt(0)" ::: "memory");
        __builtin_amdgcn_sched_barrier(0);
        asm volatile("s_barrier" ::: "memory");
        if (kt + 3 < NT) stage(cur, kt + 3);
#pragma unroll
        for (int i = 0; i < 4; ++i)
#pragma unroll
            for (int j = 0; j < 4; ++j)
                acc[i][j] = MFMA16(af[i], bfr[j], acc[i][j]);
        if (kt + 1 < NT) {
            if (kt + 3 < NT)      asm volatile("s_waitcnt vmcnt(6)" ::: "memory");
            else if (kt + 2 < NT) asm volatile("s_waitcnt vmcnt(3)" ::: "memory");
            else                  asm volatile("s_waitcnt vmcnt(0)" ::: "memory");
            asm volatile("s_barrier" ::: "memory");
        }
        cur = (cur == 2) ? 0 : cur + 1;
    }
#pragma unroll
    for (int i = 0; i < 4; ++i) {
#pragma unroll
        for (int j = 0; j < 4; ++j) {
            int crow = m0 + wr * 64 + i * 16 + lhi * 4;
            int ccol = n0 + wc * 64 + j * 16 + lrow;
            if (OBF16) {
                u16* cp = (u16*)Cv + (size_t)blockIdx.y * ((size_t)M * N)
                                   + (size_t)crow * N + ccol;
#pragma unroll
                for (int r2 = 0; r2 < 4; ++r2) cp[(size_t)r2 * N] = f2bf(acc[i][j][r2]);
            } else {
                float* cp = (float*)Cv + (size_t)blockIdx.y * ((size_t)M * N)
                                       + (size_t)crow * N + ccol;
#pragma unroll
                for (int r2 = 0; r2 < 4; ++r2) cp[(size_t)r2 * N] = acc[i][j][r2];
            }
        }
    }
}

// ---- qkv post: bf16 partial-add + RMSNorm + RoPE + cast + head-major ------
__global__ __launch_bounds__(256) void qkv_post(const u16* __restrict__ qkv0,
                                                const u16* __restrict__ qkv1,
                                                const float* __restrict__ qw,
                                                const float* __restrict__ kw,
                                                u16* __restrict__ qb,
                                                u16* __restrict__ kb,
                                                u16* __restrict__ vb) {
    const float C = 0.18033688011112042f;  // 0.125 * log2(e)
    int s = blockIdx.x;
    int t = threadIdx.x, w = t >> 6, lane = t & 63;
    const u16* row0 = qkv0 + (size_t)s * 3072;
    const u16* row1 = qkv1 + (size_t)s * 3072;
    int d2 = lane & 31;
    float inv = exp2f(-(float)d2 * (13.287712379549449f / 32.0f));
    float ang = (float)s * inv;
    float cs = cosf(ang), sn = sinf(ang);
    for (int h = w; h < 48; h += 4) {
        float v = bf2f(row0[h * 64 + lane]) + bf2f(row1[h * 64 + lane]);
        if (h < 40) {
            float ss = v * v;
#pragma unroll
            for (int m = 32; m; m >>= 1) ss += __shfl_xor(ss, m);
            float rms = rsqrtf(ss * (1.0f / 64.0f) + 1e-6f);
            float wgt = (h < 32) ? qw[lane] : kw[lane];
            v = v * rms * wgt;
            float part = __shfl_xor(v, 32);
            float rot = (lane < 32) ? -part : part;
            v = v * cs + rot * sn;
            if (h < 32)
                qb[((size_t)h * 2048 + s) * 64 + lane] = f2bf(v * C);
            else
                kb[((size_t)(h - 32) * 2048 + s) * 64 + lane] = f2bf(v);
        } else {
            vb[((size_t)(h - 40) * 2048 + s) * 64 + lane] = f2bf(v);
        }
    }
}

// ---------------- V transpose: vb[kv][s][d] -> vt[kv][d][s] ----------------
__global__ __launch_bounds__(256) void transpose_v(const u16* __restrict__ vb,
                                                   u16* __restrict__ vt) {
    int kv = blockIdx.y;
    int s0 = blockIdx.x * 256;
    __shared__ __align__(16) u16 tile[64][256];
    int t = threadIdx.x;
    int sl = t >> 3;
    int d0 = (t & 7) * 8;
#pragma unroll
    for (int j = 0; j < 8; ++j) {
        int s = sl + j * 32;
        u16x8 v = *(const u16x8*)(vb + ((size_t)kv * 2048 + s0 + s) * 64 + d0);
#pragma unroll
        for (int e = 0; e < 8; ++e) tile[d0 + e][s] = v[e];
    }
    __syncthreads();
    int d = t >> 2;
    int so = (t & 3) * 64;
#pragma unroll
    for (int j = 0; j < 8; ++j) {
        int s_local = so + j * 8;
        *(u16x8*)(vt + ((size_t)kv * 64 + d) * 2048 + s0 + s_local) =
            *(const u16x8*)&tile[d][s_local];
    }
}

// ---- flash attention v9: KVBLK=128, 64KB K/V LDS, fixed-shift softmax,
// per-group inline PV, fused w_out cast in tail blocks (bid >= 512).
__global__ __launch_bounds__(256) void attn_fa9(const u16* __restrict__ qb,
                                                const u16* __restrict__ kb,
                                                const u16* __restrict__ vt,
                                                u16* __restrict__ ab,
                                                const float* __restrict__ wout,
                                                u16* __restrict__ wb2) {
    int bid = blockIdx.x;
    if (bid >= 512) {
        int idx = (bid - 512) * 256 + threadIdx.x;
        int stride = 128 * 256;
        for (int i = idx; i < 2048 * 2048 / 4; i += stride) {
            float4 v = reinterpret_cast<const float4*>(wout)[i];
            ushort4 o;
            o.x = f2bf(v.x); o.y = f2bf(v.y); o.z = f2bf(v.z); o.w = f2bf(v.w);
            reinterpret_cast<ushort4*>(wb2)[i] = o;
        }
        return;
    }
    int qt = bid & 15, h = bid >> 4, kv = h >> 2;
    int t = threadIdx.x, w = t >> 6, l = t & 63;
    int lq = l & 31, hi = l >> 5;
    int qlo_blk = qt * 128;
    int qlo = qlo_blk + w * 32;

    __shared__ __align__(16) u16 pool[32768];
    u16* KtA = pool;
    u16* KtB = pool + 8192;
    u16* VtA = pool + 16384;
    u16* VtB = pool + 24576;

    const u16* qrow = qb + ((size_t)h * 2048 + qlo + lq) * 64 + hi * 8;
    bf16x8 qf[4];
#pragma unroll
    for (int dk = 0; dk < 4; ++dk) qf[dk] = *(const bf16x8*)(qrow + dk * 16);

    f32x16 oa = {}, ob = {};
    float lsum = 0.f;

    int kstart = qlo_blk - 511; if (kstart < 0) kstart = 0;
    int ktA = kstart >> 7;
    int ktB = qlo_blk >> 7;
    const u16* kb_h = kb + (size_t)kv * 2048 * 64;
    const u16* vt_h = vt + (size_t)kv * 64 * 2048;

    auto stage = [&](u16* Kbuf, u16* Vbuf, int kt) {
        int k0 = kt << 7;
#pragma unroll
        for (int n = 0; n < 4; ++n) {
            int c = t + n * 256;
            int kr = c >> 3, kc = c & 7;
            gld_lds16(kb_h + (size_t)(k0 + kr) * 64 + ((kc ^ (kr & 7)) << 3),
                      Kbuf + c * 8);
            int vr = c >> 4, vc = c & 15;
            gld_lds16(vt_h + (size_t)vr * 2048 + k0 + ((vc ^ (vr & 15)) << 3),
                      Vbuf + c * 8);
        }
    };

    u16 *Kc = KtA, *Kn = KtB, *Vc = VtA, *Vn = VtB;
    stage(Kc, Vc, ktA);
    for (int kt = ktA; kt <= ktB; ++kt) {
        if (kt < ktB) {
            stage(Kn, Vn, kt + 1);
            asm volatile("s_waitcnt vmcnt(8)" ::: "memory");
        } else {
            asm volatile("s_waitcnt vmcnt(0)" ::: "memory");
        }
        asm volatile("s_barrier" ::: "memory");

        int k0 = kt << 7;
#pragma unroll
        for (int g = 0; g < 4; ++g) {
            int k0g = k0 + g * 32;
            bool gact = (k0g <= qlo + 31) && (k0g + 31 >= qlo - 511);
            if (gact) {
                int krow = g * 32 + lq;
                int swz = krow & 7;
                bf16x8 kf0 = *(const bf16x8*)&Kc[krow * 64 + (((0 + hi) ^ swz) << 3)];
                bf16x8 kf1 = *(const bf16x8*)&Kc[krow * 64 + (((2 + hi) ^ swz) << 3)];
                bf16x8 kf2 = *(const bf16x8*)&Kc[krow * 64 + (((4 + hi) ^ swz) << 3)];
                bf16x8 kf3 = *(const bf16x8*)&Kc[krow * 64 + (((6 + hi) ^ swz) << 3)];
                asm volatile("s_waitcnt lgkmcnt(0)" ::: "memory");
                __builtin_amdgcn_sched_barrier(0);
                f32x16 s = {};
                s = MFMA32(kf0, qf[0], s);
                s = MFMA32(kf1, qf[1], s);
                s = MFMA32(kf2, qf[2], s);
                s = MFMA32(kf3, qf[3], s);

                bool edge = (k0g + 31 > qlo) || (qlo + 31 - k0g >= 512);
                if (edge) {
                    int q = qlo + lq;
#pragma unroll
                    for (int r = 0; r < 16; ++r) {
                        int k = k0g + (r & 3) + 8 * (r >> 2) + 4 * hi;
                        if (!((unsigned)(q - k) < 512u)) s[r] = -1e30f;
                    }
                }
                float p[16];
#pragma unroll
                for (int r = 0; r < 16; ++r) {
                    p[r] = exp2f(s[r]);
                    lsum += p[r];
                }
                u32 pk0 = cvtpk(p[0], p[1]),   pk1 = cvtpk(p[2], p[3]);
                u32 pk2 = cvtpk(p[4], p[5]),   pk3 = cvtpk(p[6], p[7]);
                u32 pk4 = cvtpk(p[8], p[9]),   pk5 = cvtpk(p[10], p[11]);
                u32 pk6 = cvtpk(p[12], p[13]), pk7 = cvtpk(p[14], p[15]);
                u32x2 r02 = __builtin_amdgcn_permlane32_swap(pk0, pk2, false, false);
                u32x2 r13 = __builtin_amdgcn_permlane32_swap(pk1, pk3, false, false);
                u32x2 r46 = __builtin_amdgcn_permlane32_swap(pk4, pk6, false, false);
                u32x2 r57 = __builtin_amdgcn_permlane32_swap(pk5, pk7, false, false);
                bf16x8 b0, b1;
                {
                    u32* bp = (u32*)&b0;
                    bp[0] = r02[0]; bp[1] = r13[0]; bp[2] = r02[1]; bp[3] = r13[1];
                    u32* bq = (u32*)&b1;
                    bq[0] = r46[0]; bq[1] = r57[0]; bq[2] = r46[1]; bq[3] = r57[1];
                }
                int vswz = lq & 15;
#pragma unroll
                for (int vi = 0; vi < 2; ++vi) {
                    int chk = g * 4 + vi * 2 + hi;
                    bf16x8 va  = *(const bf16x8*)&Vc[lq * 128 + ((chk ^ vswz) << 3)];
                    bf16x8 vb_ = *(const bf16x8*)&Vc[(lq + 32) * 128 + ((chk ^ vswz) << 3)];
                    bf16x8 bb = vi ? b1 : b0;
                    oa = MFMA32(va, bb, oa);
                    ob = MFMA32(vb_, bb, ob);
                }
            }
        }
        asm volatile("s_barrier" ::: "memory");
        u16* tk = Kc; Kc = Kn; Kn = tk;
        u16* tv = Vc; Vc = Vn; Vn = tv;
    }

    u16* smw = pool + w * (32 * 66);
    lsum += __shfl_xor(lsum, 32);
    float inv = 1.0f / lsum;
#pragma unroll
    for (int rp = 0; rp < 8; ++rp) {
        int r = rp * 2;
        int d = (r & 3) + 8 * (r >> 2) + 4 * hi;
        *(u32*)&smw[lq * 66 + d]      = cvtpk(oa[r] * inv, oa[r + 1] * inv);
        *(u32*)&smw[lq * 66 + d + 32] = cvtpk(ob[r] * inv, ob[r + 1] * inv);
    }
    asm volatile("s_waitcnt lgkmcnt(0)" ::: "memory");
    int qr = l >> 1, dbase = (l & 1) * 32;
    size_t orow = (size_t)(qlo + qr) * 2048 + h * 64 + dbase;
#pragma unroll
    for (int c2 = 0; c2 < 8; ++c2) {
        u32 w0 = *(const u32*)&smw[qr * 66 + dbase + c2 * 4];
        u32 w1 = *(const u32*)&smw[qr * 66 + dbase + c2 * 4 + 2];
        u32x2 val = { w0, w1 };
        *(u32x2*)(ab + orow + c2 * 4) = val;
    }
}

// ---------------- launch ----------------
extern "C" void kernel_launch(void* const* d_in, const int* in_sizes, int n_in,
                              void* d_out, int out_size, void* d_ws, size_t ws_size,
                              hipStream_t stream) {
    const float* x     = (const float*)d_in[0];
    const float* w_qkv = (const float*)d_in[1];
    const float* w_out = (const float*)d_in[2];
    const float* qw    = (const float*)d_in[3];
    const float* kw    = (const float*)d_in[4];
    float* out = (float*)d_out;

    char* ws = (char*)d_ws;
    u16*   x_b    = (u16*)(ws);               // 8 MB
    u16*   wB     = (u16*)(ws + 8388608);     // 12.6 MB (w_qkv)
    u16*   q_b    = (u16*)(ws);               // overlays x_b after gemm1
    u16*   k_b    = (u16*)(ws + 8388608);     // 2 MB, overlays wB
    u16*   v_b    = (u16*)(ws + 10485760);    // 2 MB
    u16*   v_t    = (u16*)(ws + 12582912);    // 2 MB
    u16*   P0     = (u16*)(ws + 20971520);    // gemm1 bf16 partials: 2 x 12.58 MB
    float* O0     = (float*)(ws + 20971520);  // gemm2 f32 partials (reuse region)
    float* O1     = (float*)(ws + 37748736);
    u16*   attn_b = (u16*)(ws + 54525952);    // 8 MB, ends 62914560
    u16*   wB2    = (u16*)(ws + 62914560);    // 8 MB (w_out bf16)

    cvt2_bf16<<<2048, 256, 0, stream>>>(x, x_b, 2048 * 2048 / 4,
                                        w_qkv, wB, 3072 * 2048 / 4);
    // gemm1: 256x256 tiles -> 8x12 = 96 tiles -> 8 XCD rects of 4(M)x3(N);
    // SPLITK=2 -> 192 blocks = ONE round; bf16 partials
    gemm_bt256<2, 4, 3, 4><<<dim3(96, 2), 512, 0, stream>>>(
        x_b, wB, P0, 2048, 3072, 2048);
    qkv_post<<<2048, 256, 0, stream>>>(P0, P0 + (size_t)2048 * 3072, qw, kw,
                                       q_b, k_b, v_b);
    transpose_v<<<dim3(8, 8), 256, 0, stream>>>(v_b, v_t);
    attn_fa9<<<640, 256, 0, stream>>>(q_b, k_b, v_t, attn_b, w_out, wB2);
    gemm_bt<2, 4, 4, 2, false><<<dim3(128, 2), 512, 0, stream>>>(
        attn_b, wB2, O0, 2048, 2048, 2048);
    reduce_add<<<1024, 256, 0, stream>>>((const float4*)O0, (const float4*)O1,
                                         (float4*)out, 2048 * 2048 / 4);
}

// Round 19
// 127.020 us; speedup vs baseline: 1.0452x; 1.0452x over previous
//
#include <hip/hip_runtime.h>

typedef unsigned short u16;
typedef unsigned int u32;
typedef __bf16 bf16x8 __attribute__((ext_vector_type(8)));
typedef float f32x4 __attribute__((ext_vector_type(4)));
typedef float f32x16 __attribute__((ext_vector_type(16)));
typedef u16 u16x8 __attribute__((ext_vector_type(8)));
typedef u32 u32x2 __attribute__((ext_vector_type(2)));
typedef u32 u32x4 __attribute__((ext_vector_type(4)));

#define MFMA16(a, b, c) __builtin_amdgcn_mfma_f32_16x16x32_bf16((a), (b), (c), 0, 0, 0)
#define MFMA32(a, b, c) __builtin_amdgcn_mfma_f32_32x32x16_bf16((a), (b), (c), 0, 0, 0)

__device__ __forceinline__ u16 f2bf(float f) {
    unsigned int u = __float_as_uint(f);
    u = (u + 0x7FFF + ((u >> 16) & 1)) >> 16;
    return (u16)u;
}

__device__ __forceinline__ float bf2f(u16 v) {
    return __uint_as_float(((u32)v) << 16);
}

__device__ __forceinline__ u32 cvtpk(float a, float b) {
    u32 d;
    asm("v_cvt_pk_bf16_f32 %0, %1, %2" : "=v"(d) : "v"(a), "v"(b));
    return d;
}

__device__ __forceinline__ void gld_lds16(const u16* g, u16* l) {
    __builtin_amdgcn_global_load_lds(
        (const __attribute__((address_space(1))) unsigned int*)g,
        (__attribute__((address_space(3))) unsigned int*)l, 16, 0, 0);
}

// ---------------- fp32 -> bf16 cast, two tensors in one dispatch ----------------
__global__ __launch_bounds__(256) void cvt2_bf16(const float* __restrict__ in1,
                                                 u16* __restrict__ out1, int n41,
                                                 const float* __restrict__ in2,
                                                 u16* __restrict__ out2, int n42) {
    int idx = blockIdx.x * blockDim.x + threadIdx.x;
    int stride = gridDim.x * blockDim.x;
    for (int i = idx; i < n41; i += stride) {
        float4 v = reinterpret_cast<const float4*>(in1)[i];
        ushort4 o;
        o.x = f2bf(v.x); o.y = f2bf(v.y); o.z = f2bf(v.z); o.w = f2bf(v.w);
        reinterpret_cast<ushort4*>(out1)[i] = o;
    }
    for (int i = idx; i < n42; i += stride) {
        float4 v = reinterpret_cast<const float4*>(in2)[i];
        ushort4 o;
        o.x = f2bf(v.x); o.y = f2bf(v.y); o.z = f2bf(v.z); o.w = f2bf(v.w);
        reinterpret_cast<ushort4*>(out2)[i] = o;
    }
}

// ---------------- partial-sum reduce: o = a + b ----------------
__global__ __launch_bounds__(256) void reduce_add(const float4* __restrict__ a,
                                                  const float4* __restrict__ b,
                                                  float4* __restrict__ o, int n4) {
    int idx = blockIdx.x * blockDim.x + threadIdx.x;
    int stride = gridDim.x * blockDim.x;
    for (int i = idx; i < n4; i += stride) {
        float4 va = a[i], vb = b[i];
        float4 vo = {va.x + vb.x, va.y + vb.y, va.z + vb.z, va.w + vb.w};
        o[i] = vo;
    }
}

// ---- bf16 GEMM: 128x256 tile, 8 waves, depth-3 pipeline, T2 swizzle, XCD rects ----
template <int SPLITK, int RM, int RN, int XN, bool OBF16>
__global__ __launch_bounds__(512) void gemm_bt(const u16* __restrict__ A,
                                               const u16* __restrict__ B,
                                               void* __restrict__ Cv,
                                               int M, int N, int K) {
    __shared__ __align__(16) u16 As[3][128 * 32];
    __shared__ __align__(16) u16 Bs[3][256 * 32];

    int bid = blockIdx.x;
    int xcd = bid & 7;
    int r = bid >> 3;
    int tm = (xcd / XN) * RM + (r / RN);
    int tn = (xcd % XN) * RN + (r % RN);
    int m0 = tm << 7, n0 = tn << 8;

    int Ks = K / SPLITK;
    int kbase = blockIdx.y * Ks;

    int t = threadIdx.x;
    int w = t >> 6, l = t & 63, lrow = l & 15, lhi = l >> 4;
    int wr = w >> 2, wc = w & 3;

    int rowA = t >> 2;
    int col0 = (((t & 3) ^ ((t >> 3) & 3)) << 3);

    const u16* Ag = A + (size_t)m0 * K + kbase;
    const u16* Bg = B + (size_t)n0 * K + kbase;

    auto stage = [&](int sbuf, int kt) {
        int k0 = kt << 5;
        gld_lds16(Ag + (size_t)rowA * K + k0 + col0, &As[sbuf][t * 8]);
        gld_lds16(Bg + (size_t)rowA * K + k0 + col0, &Bs[sbuf][t * 8]);
        gld_lds16(Bg + (size_t)(rowA + 128) * K + k0 + col0, &Bs[sbuf][t * 8 + 4096]);
    };

    f32x4 acc[4][4] = {};
    int NT = Ks >> 5;
    stage(0, 0); stage(1, 1); stage(2, 2);
    asm volatile("s_waitcnt vmcnt(6)" ::: "memory");
    asm volatile("s_barrier" ::: "memory");
    int cur = 0;
    for (int kt = 0; kt < NT; ++kt) {
        bf16x8 af[4], bfr[4];
#pragma unroll
        for (int i = 0; i < 4; ++i) {
            int row = wr * 64 + i * 16 + lrow;
            af[i] = *(const bf16x8*)&As[cur][row * 32 + ((lhi ^ ((row >> 1) & 3)) << 3)];
        }
#pragma unroll
        for (int j = 0; j < 4; ++j) {
            int row = wc * 64 + j * 16 + lrow;
            bfr[j] = *(const bf16x8*)&Bs[cur][row * 32 + ((lhi ^ ((row >> 1) & 3)) << 3)];
        }
        asm volatile("s_waitcnt lgkmcnt(0)" ::: "memory");
        __builtin_amdgcn_sched_barrier(0);
        asm volatile("s_barrier" ::: "memory");
        if (kt + 3 < NT) stage(cur, kt + 3);
#pragma unroll
        for (int i = 0; i < 4; ++i)
#pragma unroll
            for (int j = 0; j < 4; ++j)
                acc[i][j] = MFMA16(af[i], bfr[j], acc[i][j]);
        if (kt + 1 < NT) {
            if (kt + 3 < NT)      asm volatile("s_waitcnt vmcnt(6)" ::: "memory");
            else if (kt + 2 < NT) asm volatile("s_waitcnt vmcnt(3)" ::: "memory");
            else                  asm volatile("s_waitcnt vmcnt(0)" ::: "memory");
            asm volatile("s_barrier" ::: "memory");
        }
        cur = (cur == 2) ? 0 : cur + 1;
    }
#pragma unroll
    for (int i = 0; i < 4; ++i) {
#pragma unroll
        for (int j = 0; j < 4; ++j) {
            int crow = m0 + wr * 64 + i * 16 + lhi * 4;
            int ccol = n0 + wc * 64 + j * 16 + lrow;
            if (OBF16) {
                u16* cp = (u16*)Cv + (size_t)blockIdx.y * ((size_t)M * N)
                                   + (size_t)crow * N + ccol;
#pragma unroll
                for (int r2 = 0; r2 < 4; ++r2) cp[(size_t)r2 * N] = f2bf(acc[i][j][r2]);
            } else {
                float* cp = (float*)Cv + (size_t)blockIdx.y * ((size_t)M * N)
                                       + (size_t)crow * N + ccol;
#pragma unroll
                for (int r2 = 0; r2 < 4; ++r2) cp[(size_t)r2 * N] = acc[i][j][r2];
            }
        }
    }
}

// ---- qkv post: bf16 partial-add + RMSNorm + RoPE + cast + head-major ------
__global__ __launch_bounds__(256) void qkv_post(const u16* __restrict__ qkv0,
                                                const u16* __restrict__ qkv1,
                                                const float* __restrict__ qw,
                                                const float* __restrict__ kw,
                                                u16* __restrict__ qb,
                                                u16* __restrict__ kb,
                                                u16* __restrict__ vb) {
    const float C = 0.18033688011112042f;  // 0.125 * log2(e)
    int s = blockIdx.x;
    int t = threadIdx.x, w = t >> 6, lane = t & 63;
    const u16* row0 = qkv0 + (size_t)s * 3072;
    const u16* row1 = qkv1 + (size_t)s * 3072;
    int d2 = lane & 31;
    float inv = exp2f(-(float)d2 * (13.287712379549449f / 32.0f));
    float ang = (float)s * inv;
    float cs = cosf(ang), sn = sinf(ang);
    for (int h = w; h < 48; h += 4) {
        float v = bf2f(row0[h * 64 + lane]) + bf2f(row1[h * 64 + lane]);
        if (h < 40) {
            float ss = v * v;
#pragma unroll
            for (int m = 32; m; m >>= 1) ss += __shfl_xor(ss, m);
            float rms = rsqrtf(ss * (1.0f / 64.0f) + 1e-6f);
            float wgt = (h < 32) ? qw[lane] : kw[lane];
            v = v * rms * wgt;
            float part = __shfl_xor(v, 32);
            float rot = (lane < 32) ? -part : part;
            v = v * cs + rot * sn;
            if (h < 32)
                qb[((size_t)h * 2048 + s) * 64 + lane] = f2bf(v * C);
            else
                kb[((size_t)(h - 32) * 2048 + s) * 64 + lane] = f2bf(v);
        } else {
            vb[((size_t)(h - 40) * 2048 + s) * 64 + lane] = f2bf(v);
        }
    }
}

// ---------------- V transpose: vb[kv][s][d] -> vt[kv][d][s] ----------------
__global__ __launch_bounds__(256) void transpose_v(const u16* __restrict__ vb,
                                                   u16* __restrict__ vt) {
    int kv = blockIdx.y;
    int s0 = blockIdx.x * 256;
    __shared__ __align__(16) u16 tile[64][256];
    int t = threadIdx.x;
    int sl = t >> 3;
    int d0 = (t & 7) * 8;
#pragma unroll
    for (int j = 0; j < 8; ++j) {
        int s = sl + j * 32;
        u16x8 v = *(const u16x8*)(vb + ((size_t)kv * 2048 + s0 + s) * 64 + d0);
#pragma unroll
        for (int e = 0; e < 8; ++e) tile[d0 + e][s] = v[e];
    }
    __syncthreads();
    int d = t >> 2;
    int so = (t & 3) * 64;
#pragma unroll
    for (int j = 0; j < 8; ++j) {
        int s_local = so + j * 8;
        *(u16x8*)(vt + ((size_t)kv * 64 + d) * 2048 + s0 + s_local) =
            *(const u16x8*)&tile[d][s_local];
    }
}

// ---- flash attention v10: KVBLK=128, pair-batched groups for 2x ILP.
// Per pair: both QK chains independent; V ds_reads issued before softmax VALU;
// 32 exp2 as one independent block; PV 8 MFMAs. Dead groups masked (p=0), not
// branched. Fused w_out cast in tail blocks (bid >= 512).
__global__ __launch_bounds__(256) void attn_fa10(const u16* __restrict__ qb,
                                                 const u16* __restrict__ kb,
                                                 const u16* __restrict__ vt,
                                                 u16* __restrict__ ab,
                                                 const float* __restrict__ wout,
                                                 u16* __restrict__ wb2) {
    int bid = blockIdx.x;
    if (bid >= 512) {
        int idx = (bid - 512) * 256 + threadIdx.x;
        int stride = 128 * 256;
        for (int i = idx; i < 2048 * 2048 / 4; i += stride) {
            float4 v = reinterpret_cast<const float4*>(wout)[i];
            ushort4 o;
            o.x = f2bf(v.x); o.y = f2bf(v.y); o.z = f2bf(v.z); o.w = f2bf(v.w);
            reinterpret_cast<ushort4*>(wb2)[i] = o;
        }
        return;
    }
    int qt = bid & 15, h = bid >> 4, kv = h >> 2;
    int t = threadIdx.x, w = t >> 6, l = t & 63;
    int lq = l & 31, hi = l >> 5;
    int qlo_blk = qt * 128;
    int qlo = qlo_blk + w * 32;

    __shared__ __align__(16) u16 pool[32768];
    u16* KtA = pool;
    u16* KtB = pool + 8192;
    u16* VtA = pool + 16384;
    u16* VtB = pool + 24576;

    const u16* qrow = qb + ((size_t)h * 2048 + qlo + lq) * 64 + hi * 8;
    bf16x8 qf[4];
#pragma unroll
    for (int dk = 0; dk < 4; ++dk) qf[dk] = *(const bf16x8*)(qrow + dk * 16);

    f32x16 oa = {}, ob = {};
    float lsum = 0.f;

    int kstart = qlo_blk - 511; if (kstart < 0) kstart = 0;
    int ktA = kstart >> 7;
    int ktB = qlo_blk >> 7;
    const u16* kb_h = kb + (size_t)kv * 2048 * 64;
    const u16* vt_h = vt + (size_t)kv * 64 * 2048;

    auto stage = [&](u16* Kbuf, u16* Vbuf, int kt) {
        int k0 = kt << 7;
#pragma unroll
        for (int n = 0; n < 4; ++n) {
            int c = t + n * 256;
            int kr = c >> 3, kc = c & 7;
            gld_lds16(kb_h + (size_t)(k0 + kr) * 64 + ((kc ^ (kr & 7)) << 3),
                      Kbuf + c * 8);
            int vr = c >> 4, vc = c & 15;
            gld_lds16(vt_h + (size_t)vr * 2048 + k0 + ((vc ^ (vr & 15)) << 3),
                      Vbuf + c * 8);
        }
    };

    u16 *Kc = KtA, *Kn = KtB, *Vc = VtA, *Vn = VtB;
    stage(Kc, Vc, ktA);
    for (int kt = ktA; kt <= ktB; ++kt) {
        if (kt < ktB) {
            stage(Kn, Vn, kt + 1);
            asm volatile("s_waitcnt vmcnt(8)" ::: "memory");
        } else {
            asm volatile("s_waitcnt vmcnt(0)" ::: "memory");
        }
        asm volatile("s_barrier" ::: "memory");

        int k0 = kt << 7;
        int vswz = lq & 15;
#pragma unroll
        for (int pp = 0; pp < 2; ++pp) {
            int g0 = pp * 2, g1 = pp * 2 + 1;
            int k00 = k0 + g0 * 32, k01 = k0 + g1 * 32;
            bool act0 = (k00 <= qlo + 31) && (k00 + 31 >= qlo - 511);
            bool act1 = (k01 <= qlo + 31) && (k01 + 31 >= qlo - 511);
            if (!(act0 || act1)) continue;

            // --- K fragments for both groups (8 ds_read_b128) ---
            int kr0 = g0 * 32 + lq, kr1 = g1 * 32 + lq;
            int sz0 = kr0 & 7, sz1 = kr1 & 7;
            bf16x8 ka0 = *(const bf16x8*)&Kc[kr0 * 64 + (((0 + hi) ^ sz0) << 3)];
            bf16x8 ka1 = *(const bf16x8*)&Kc[kr0 * 64 + (((2 + hi) ^ sz0) << 3)];
            bf16x8 ka2 = *(const bf16x8*)&Kc[kr0 * 64 + (((4 + hi) ^ sz0) << 3)];
            bf16x8 ka3 = *(const bf16x8*)&Kc[kr0 * 64 + (((6 + hi) ^ sz0) << 3)];
            bf16x8 kb0 = *(const bf16x8*)&Kc[kr1 * 64 + (((0 + hi) ^ sz1) << 3)];
            bf16x8 kb1 = *(const bf16x8*)&Kc[kr1 * 64 + (((2 + hi) ^ sz1) << 3)];
            bf16x8 kb2 = *(const bf16x8*)&Kc[kr1 * 64 + (((4 + hi) ^ sz1) << 3)];
            bf16x8 kb3 = *(const bf16x8*)&Kc[kr1 * 64 + (((6 + hi) ^ sz1) << 3)];
            asm volatile("s_waitcnt lgkmcnt(0)" ::: "memory");
            __builtin_amdgcn_sched_barrier(0);

            // --- two independent QK chains ---
            f32x16 s0 = {}, s1 = {};
            s0 = MFMA32(ka0, qf[0], s0);  s1 = MFMA32(kb0, qf[0], s1);
            s0 = MFMA32(ka1, qf[1], s0);  s1 = MFMA32(kb1, qf[1], s1);
            s0 = MFMA32(ka2, qf[2], s0);  s1 = MFMA32(kb2, qf[2], s1);
            s0 = MFMA32(ka3, qf[3], s0);  s1 = MFMA32(kb3, qf[3], s1);

            // --- V fragments issued early (latency hides under softmax) ---
            bf16x8 va[2][2], vbl[2][2];
#pragma unroll
            for (int vi = 0; vi < 2; ++vi) {
                int c0 = ((g0 * 4 + vi * 2 + hi) ^ vswz) << 3;
                int c1 = ((g1 * 4 + vi * 2 + hi) ^ vswz) << 3;
                va[0][vi]  = *(const bf16x8*)&Vc[lq * 128 + c0];
                vbl[0][vi] = *(const bf16x8*)&Vc[(lq + 32) * 128 + c0];
                va[1][vi]  = *(const bf16x8*)&Vc[lq * 128 + c1];
                vbl[1][vi] = *(const bf16x8*)&Vc[(lq + 32) * 128 + c1];
            }

            // --- masks (dead/edge groups -> -1e30 -> p = 0) ---
            int q = qlo + lq;
            bool edge0 = (k00 + 31 > qlo) || (qlo + 31 - k00 >= 512);
            if (edge0) {
#pragma unroll
                for (int r = 0; r < 16; ++r) {
                    int k = k00 + (r & 3) + 8 * (r >> 2) + 4 * hi;
                    if (!((unsigned)(q - k) < 512u)) s0[r] = -1e30f;
                }
            }
            bool edge1 = (k01 + 31 > qlo) || (qlo + 31 - k01 >= 512);
            if (edge1) {
#pragma unroll
                for (int r = 0; r < 16; ++r) {
                    int k = k01 + (r & 3) + 8 * (r >> 2) + 4 * hi;
                    if (!((unsigned)(q - k) < 512u)) s1[r] = -1e30f;
                }
            }

            // --- 32 independent exp2 + sum ---
            float p0[16], p1[16];
#pragma unroll
            for (int r = 0; r < 16; ++r) {
                p0[r] = exp2f(s0[r]);
                p1[r] = exp2f(s1[r]);
                lsum += p0[r] + p1[r];
            }

            // --- pack both groups ---
            u32 a0 = cvtpk(p0[0], p0[1]),   a1 = cvtpk(p0[2], p0[3]);
            u32 a2 = cvtpk(p0[4], p0[5]),   a3 = cvtpk(p0[6], p0[7]);
            u32 a4 = cvtpk(p0[8], p0[9]),   a5 = cvtpk(p0[10], p0[11]);
            u32 a6 = cvtpk(p0[12], p0[13]), a7 = cvtpk(p0[14], p0[15]);
            u32 c0 = cvtpk(p1[0], p1[1]),   c1 = cvtpk(p1[2], p1[3]);
            u32 c2 = cvtpk(p1[4], p1[5]),   c3 = cvtpk(p1[6], p1[7]);
            u32 c4 = cvtpk(p1[8], p1[9]),   c5 = cvtpk(p1[10], p1[11]);
            u32 c6 = cvtpk(p1[12], p1[13]), c7 = cvtpk(p1[14], p1[15]);
            u32x2 ra02 = __builtin_amdgcn_permlane32_swap(a0, a2, false, false);
            u32x2 ra13 = __builtin_amdgcn_permlane32_swap(a1, a3, false, false);
            u32x2 ra46 = __builtin_amdgcn_permlane32_swap(a4, a6, false, false);
            u32x2 ra57 = __builtin_amdgcn_permlane32_swap(a5, a7, false, false);
            u32x2 rc02 = __builtin_amdgcn_permlane32_swap(c0, c2, false, false);
            u32x2 rc13 = __builtin_amdgcn_permlane32_swap(c1, c3, false, false);
            u32x2 rc46 = __builtin_amdgcn_permlane32_swap(c4, c6, false, false);
            u32x2 rc57 = __builtin_amdgcn_permlane32_swap(c5, c7, false, false);
            bf16x8 b0g0, b1g0, b0g1, b1g1;
            {
                u32* bp = (u32*)&b0g0;
                bp[0] = ra02[0]; bp[1] = ra13[0]; bp[2] = ra02[1]; bp[3] = ra13[1];
                u32* bq = (u32*)&b1g0;
                bq[0] = ra46[0]; bq[1] = ra57[0]; bq[2] = ra46[1]; bq[3] = ra57[1];
                u32* cp = (u32*)&b0g1;
                cp[0] = rc02[0]; cp[1] = rc13[0]; cp[2] = rc02[1]; cp[3] = rc13[1];
                u32* cq = (u32*)&b1g1;
                cq[0] = rc46[0]; cq[1] = rc57[0]; cq[2] = rc46[1]; cq[3] = rc57[1];
            }

            // --- PV: 8 MFMAs, alternating oa/ob chains ---
            oa = MFMA32(va[0][0], b0g0, oa);  ob = MFMA32(vbl[0][0], b0g0, ob);
            oa = MFMA32(va[0][1], b1g0, oa);  ob = MFMA32(vbl[0][1], b1g0, ob);
            oa = MFMA32(va[1][0], b0g1, oa);  ob = MFMA32(vbl[1][0], b0g1, ob);
            oa = MFMA32(va[1][1], b1g1, oa);  ob = MFMA32(vbl[1][1], b1g1, ob);
        }
        asm volatile("s_barrier" ::: "memory");
        u16* tk = Kc; Kc = Kn; Kn = tk;
        u16* tv = Vc; Vc = Vn; Vn = tv;
    }

    u16* smw = pool + w * (32 * 66);
    lsum += __shfl_xor(lsum, 32);
    float inv = 1.0f / lsum;
#pragma unroll
    for (int rp = 0; rp < 8; ++rp) {
        int r = rp * 2;
        int d = (r & 3) + 8 * (r >> 2) + 4 * hi;
        *(u32*)&smw[lq * 66 + d]      = cvtpk(oa[r] * inv, oa[r + 1] * inv);
        *(u32*)&smw[lq * 66 + d + 32] = cvtpk(ob[r] * inv, ob[r + 1] * inv);
    }
    asm volatile("s_waitcnt lgkmcnt(0)" ::: "memory");
    int qr = l >> 1, dbase = (l & 1) * 32;
    size_t orow = (size_t)(qlo + qr) * 2048 + h * 64 + dbase;
#pragma unroll
    for (int c2 = 0; c2 < 8; ++c2) {
        u32 w0 = *(const u32*)&smw[qr * 66 + dbase + c2 * 4];
        u32 w1 = *(const u32*)&smw[qr * 66 + dbase + c2 * 4 + 2];
        u32x2 val = { w0, w1 };
        *(u32x2*)(ab + orow + c2 * 4) = val;
    }
}

// ---------------- launch ----------------
extern "C" void kernel_launch(void* const* d_in, const int* in_sizes, int n_in,
                              void* d_out, int out_size, void* d_ws, size_t ws_size,
                              hipStream_t stream) {
    const float* x     = (const float*)d_in[0];
    const float* w_qkv = (const float*)d_in[1];
    const float* w_out = (const float*)d_in[2];
    const float* qw    = (const float*)d_in[3];
    const float* kw    = (const float*)d_in[4];
    float* out = (float*)d_out;

    char* ws = (char*)d_ws;
    u16*   x_b    = (u16*)(ws);               // 8 MB
    u16*   wB     = (u16*)(ws + 8388608);     // 12.6 MB (w_qkv)
    u16*   q_b    = (u16*)(ws);               // overlays x_b after gemm1
    u16*   k_b    = (u16*)(ws + 8388608);     // 2 MB, overlays wB
    u16*   v_b    = (u16*)(ws + 10485760);    // 2 MB
    u16*   v_t    = (u16*)(ws + 12582912);    // 2 MB
    u16*   P0     = (u16*)(ws + 20971520);    // gemm1 bf16 partials: 2 x 12.58 MB
    float* O0     = (float*)(ws + 20971520);  // gemm2 f32 partials (reuse region)
    float* O1     = (float*)(ws + 37748736);
    u16*   attn_b = (u16*)(ws + 54525952);    // 8 MB, ends 62914560
    u16*   wB2    = (u16*)(ws + 62914560);    // 8 MB (w_out bf16)

    cvt2_bf16<<<2048, 256, 0, stream>>>(x, x_b, 2048 * 2048 / 4,
                                        w_qkv, wB, 3072 * 2048 / 4);
    // gemm1: 16x12 tile grid (128x256 tiles) -> 8 XCD rects of 8(M)x3(N); bf16 partials
    gemm_bt<2, 8, 3, 4, true><<<dim3(192, 2), 512, 0, stream>>>(
        x_b, wB, P0, 2048, 3072, 2048);
    qkv_post<<<2048, 256, 0, stream>>>(P0, P0 + (size_t)2048 * 3072, qw, kw,
                                       q_b, k_b, v_b);
    transpose_v<<<dim3(8, 8), 256, 0, stream>>>(v_b, v_t);
    attn_fa10<<<640, 256, 0, stream>>>(q_b, k_b, v_t, attn_b, w_out, wB2);
    gemm_bt<2, 4, 4, 2, false><<<dim3(128, 2), 512, 0, stream>>>(
        attn_b, wB2, O0, 2048, 2048, 2048);
    reduce_add<<<1024, 256, 0, stream>>>((const float4*)O0, (const float4*)O1,
                                         (float4*)out, 2048 * 2048 / 4);
}

// Round 20
// 126.879 us; speedup vs baseline: 1.0463x; 1.0011x over previous
//
#include <hip/hip_runtime.h>

typedef unsigned short u16;
typedef unsigned int u32;
typedef __bf16 bf16x8 __attribute__((ext_vector_type(8)));
typedef float f32x4 __attribute__((ext_vector_type(4)));
typedef float f32x16 __attribute__((ext_vector_type(16)));
typedef u16 u16x8 __attribute__((ext_vector_type(8)));
typedef u32 u32x2 __attribute__((ext_vector_type(2)));
typedef u32 u32x4 __attribute__((ext_vector_type(4)));

#define MFMA16(a, b, c) __builtin_amdgcn_mfma_f32_16x16x32_bf16((a), (b), (c), 0, 0, 0)
#define MFMA32(a, b, c) __builtin_amdgcn_mfma_f32_32x32x16_bf16((a), (b), (c), 0, 0, 0)

__device__ __forceinline__ u16 f2bf(float f) {
    unsigned int u = __float_as_uint(f);
    u = (u + 0x7FFF + ((u >> 16) & 1)) >> 16;
    return (u16)u;
}

__device__ __forceinline__ float bf2f(u16 v) {
    return __uint_as_float(((u32)v) << 16);
}

__device__ __forceinline__ u32 cvtpk(float a, float b) {
    u32 d;
    asm("v_cvt_pk_bf16_f32 %0, %1, %2" : "=v"(d) : "v"(a), "v"(b));
    return d;
}

__device__ __forceinline__ void gld_lds16(const u16* g, u16* l) {
    __builtin_amdgcn_global_load_lds(
        (const __attribute__((address_space(1))) unsigned int*)g,
        (__attribute__((address_space(3))) unsigned int*)l, 16, 0, 0);
}

// ---------------- fp32 -> bf16 cast, two tensors in one dispatch ----------------
__global__ __launch_bounds__(256) void cvt2_bf16(const float* __restrict__ in1,
                                                 u16* __restrict__ out1, int n41,
                                                 const float* __restrict__ in2,
                                                 u16* __restrict__ out2, int n42) {
    int idx = blockIdx.x * blockDim.x + threadIdx.x;
    int stride = gridDim.x * blockDim.x;
    for (int i = idx; i < n41; i += stride) {
        float4 v = reinterpret_cast<const float4*>(in1)[i];
        ushort4 o;
        o.x = f2bf(v.x); o.y = f2bf(v.y); o.z = f2bf(v.z); o.w = f2bf(v.w);
        reinterpret_cast<ushort4*>(out1)[i] = o;
    }
    for (int i = idx; i < n42; i += stride) {
        float4 v = reinterpret_cast<const float4*>(in2)[i];
        ushort4 o;
        o.x = f2bf(v.x); o.y = f2bf(v.y); o.z = f2bf(v.z); o.w = f2bf(v.w);
        reinterpret_cast<ushort4*>(out2)[i] = o;
    }
}

// ---------------- bf16 partial-sum reduce: out_f32 = a_bf16 + b_bf16 ----------------
__global__ __launch_bounds__(256) void reduce_add_bf(const u16x8* __restrict__ a,
                                                     const u16x8* __restrict__ b,
                                                     float4* __restrict__ o, int n8) {
    int idx = blockIdx.x * blockDim.x + threadIdx.x;
    int stride = gridDim.x * blockDim.x;
    for (int i = idx; i < n8; i += stride) {
        u16x8 va = a[i], vb = b[i];
        float4 o0, o1;
        o0.x = bf2f(va[0]) + bf2f(vb[0]);
        o0.y = bf2f(va[1]) + bf2f(vb[1]);
        o0.z = bf2f(va[2]) + bf2f(vb[2]);
        o0.w = bf2f(va[3]) + bf2f(vb[3]);
        o1.x = bf2f(va[4]) + bf2f(vb[4]);
        o1.y = bf2f(va[5]) + bf2f(vb[5]);
        o1.z = bf2f(va[6]) + bf2f(vb[6]);
        o1.w = bf2f(va[7]) + bf2f(vb[7]);
        o[i * 2] = o0;
        o[i * 2 + 1] = o1;
    }
}

// ---- bf16 GEMM: 128x256 tile, 8 waves, depth-3 pipeline, T2 swizzle, XCD rects ----
// Always bf16 output (both gemms now write bf16 partials).
template <int SPLITK, int RM, int RN, int XN>
__global__ __launch_bounds__(512) void gemm_bt(const u16* __restrict__ A,
                                               const u16* __restrict__ B,
                                               u16* __restrict__ C,
                                               int M, int N, int K) {
    __shared__ __align__(16) u16 As[3][128 * 32];
    __shared__ __align__(16) u16 Bs[3][256 * 32];

    int bid = blockIdx.x;
    int xcd = bid & 7;
    int r = bid >> 3;
    int tm = (xcd / XN) * RM + (r / RN);
    int tn = (xcd % XN) * RN + (r % RN);
    int m0 = tm << 7, n0 = tn << 8;

    int Ks = K / SPLITK;
    int kbase = blockIdx.y * Ks;

    int t = threadIdx.x;
    int w = t >> 6, l = t & 63, lrow = l & 15, lhi = l >> 4;
    int wr = w >> 2, wc = w & 3;

    int rowA = t >> 2;
    int col0 = (((t & 3) ^ ((t >> 3) & 3)) << 3);

    const u16* Ag = A + (size_t)m0 * K + kbase;
    const u16* Bg = B + (size_t)n0 * K + kbase;

    auto stage = [&](int sbuf, int kt) {
        int k0 = kt << 5;
        gld_lds16(Ag + (size_t)rowA * K + k0 + col0, &As[sbuf][t * 8]);
        gld_lds16(Bg + (size_t)rowA * K + k0 + col0, &Bs[sbuf][t * 8]);
        gld_lds16(Bg + (size_t)(rowA + 128) * K + k0 + col0, &Bs[sbuf][t * 8 + 4096]);
    };

    f32x4 acc[4][4] = {};
    int NT = Ks >> 5;
    stage(0, 0); stage(1, 1); stage(2, 2);
    asm volatile("s_waitcnt vmcnt(6)" ::: "memory");
    asm volatile("s_barrier" ::: "memory");
    int cur = 0;
    for (int kt = 0; kt < NT; ++kt) {
        bf16x8 af[4], bfr[4];
#pragma unroll
        for (int i = 0; i < 4; ++i) {
            int row = wr * 64 + i * 16 + lrow;
            af[i] = *(const bf16x8*)&As[cur][row * 32 + ((lhi ^ ((row >> 1) & 3)) << 3)];
        }
#pragma unroll
        for (int j = 0; j < 4; ++j) {
            int row = wc * 64 + j * 16 + lrow;
            bfr[j] = *(const bf16x8*)&Bs[cur][row * 32 + ((lhi ^ ((row >> 1) & 3)) << 3)];
        }
        asm volatile("s_waitcnt lgkmcnt(0)" ::: "memory");
        __builtin_amdgcn_sched_barrier(0);
        asm volatile("s_barrier" ::: "memory");
        if (kt + 3 < NT) stage(cur, kt + 3);
        __builtin_amdgcn_s_setprio(1);
#pragma unroll
        for (int i = 0; i < 4; ++i)
#pragma unroll
            for (int j = 0; j < 4; ++j)
                acc[i][j] = MFMA16(af[i], bfr[j], acc[i][j]);
        __builtin_amdgcn_s_setprio(0);
        if (kt + 1 < NT) {
            if (kt + 3 < NT)      asm volatile("s_waitcnt vmcnt(6)" ::: "memory");
            else if (kt + 2 < NT) asm volatile("s_waitcnt vmcnt(3)" ::: "memory");
            else                  asm volatile("s_waitcnt vmcnt(0)" ::: "memory");
            asm volatile("s_barrier" ::: "memory");
        }
        cur = (cur == 2) ? 0 : cur + 1;
    }
#pragma unroll
    for (int i = 0; i < 4; ++i) {
#pragma unroll
        for (int j = 0; j < 4; ++j) {
            int crow = m0 + wr * 64 + i * 16 + lhi * 4;
            int ccol = n0 + wc * 64 + j * 16 + lrow;
            u16* cp = C + (size_t)blockIdx.y * ((size_t)M * N) + (size_t)crow * N + ccol;
#pragma unroll
            for (int r2 = 0; r2 < 4; ++r2) cp[(size_t)r2 * N] = f2bf(acc[i][j][r2]);
        }
    }
}

// ---- qkv post: bf16 partial-add + RMSNorm + RoPE + cast + head-major ------
__global__ __launch_bounds__(256) void qkv_post(const u16* __restrict__ qkv0,
                                                const u16* __restrict__ qkv1,
                                                const float* __restrict__ qw,
                                                const float* __restrict__ kw,
                                                u16* __restrict__ qb,
                                                u16* __restrict__ kb,
                                                u16* __restrict__ vb) {
    const float C = 0.18033688011112042f;  // 0.125 * log2(e)
    int s = blockIdx.x;
    int t = threadIdx.x, w = t >> 6, lane = t & 63;
    const u16* row0 = qkv0 + (size_t)s * 3072;
    const u16* row1 = qkv1 + (size_t)s * 3072;
    int d2 = lane & 31;
    float inv = exp2f(-(float)d2 * (13.287712379549449f / 32.0f));
    float ang = (float)s * inv;
    float cs = cosf(ang), sn = sinf(ang);
    for (int h = w; h < 48; h += 4) {
        float v = bf2f(row0[h * 64 + lane]) + bf2f(row1[h * 64 + lane]);
        if (h < 40) {
            float ss = v * v;
#pragma unroll
            for (int m = 32; m; m >>= 1) ss += __shfl_xor(ss, m);
            float rms = rsqrtf(ss * (1.0f / 64.0f) + 1e-6f);
            float wgt = (h < 32) ? qw[lane] : kw[lane];
            v = v * rms * wgt;
            float part = __shfl_xor(v, 32);
            float rot = (lane < 32) ? -part : part;
            v = v * cs + rot * sn;
            if (h < 32)
                qb[((size_t)h * 2048 + s) * 64 + lane] = f2bf(v * C);
            else
                kb[((size_t)(h - 32) * 2048 + s) * 64 + lane] = f2bf(v);
        } else {
            vb[((size_t)(h - 40) * 2048 + s) * 64 + lane] = f2bf(v);
        }
    }
}

// ---------------- V transpose: vb[kv][s][d] -> vt[kv][d][s] ----------------
__global__ __launch_bounds__(256) void transpose_v(const u16* __restrict__ vb,
                                                   u16* __restrict__ vt) {
    int kv = blockIdx.y;
    int s0 = blockIdx.x * 256;
    __shared__ __align__(16) u16 tile[64][256];
    int t = threadIdx.x;
    int sl = t >> 3;
    int d0 = (t & 7) * 8;
#pragma unroll
    for (int j = 0; j < 8; ++j) {
        int s = sl + j * 32;
        u16x8 v = *(const u16x8*)(vb + ((size_t)kv * 2048 + s0 + s) * 64 + d0);
#pragma unroll
        for (int e = 0; e < 8; ++e) tile[d0 + e][s] = v[e];
    }
    __syncthreads();
    int d = t >> 2;
    int so = (t & 3) * 64;
#pragma unroll
    for (int j = 0; j < 8; ++j) {
        int s_local = so + j * 8;
        *(u16x8*)(vt + ((size_t)kv * 64 + d) * 2048 + s0 + s_local) =
            *(const u16x8*)&tile[d][s_local];
    }
}

// ---- flash attention v10b: KVBLK=128, pair-batched groups, T5 setprio on MFMA
// clusters, fixed-shift softmax, fused w_out cast in tail blocks (bid >= 512).
__global__ __launch_bounds__(256) void attn_fa10(const u16* __restrict__ qb,
                                                 const u16* __restrict__ kb,
                                                 const u16* __restrict__ vt,
                                                 u16* __restrict__ ab,
                                                 const float* __restrict__ wout,
                                                 u16* __restrict__ wb2) {
    int bid = blockIdx.x;
    if (bid >= 512) {
        int idx = (bid - 512) * 256 + threadIdx.x;
        int stride = 128 * 256;
        for (int i = idx; i < 2048 * 2048 / 4; i += stride) {
            float4 v = reinterpret_cast<const float4*>(wout)[i];
            ushort4 o;
            o.x = f2bf(v.x); o.y = f2bf(v.y); o.z = f2bf(v.z); o.w = f2bf(v.w);
            reinterpret_cast<ushort4*>(wb2)[i] = o;
        }
        return;
    }
    int qt = bid & 15, h = bid >> 4, kv = h >> 2;
    int t = threadIdx.x, w = t >> 6, l = t & 63;
    int lq = l & 31, hi = l >> 5;
    int qlo_blk = qt * 128;
    int qlo = qlo_blk + w * 32;

    __shared__ __align__(16) u16 pool[32768];
    u16* KtA = pool;
    u16* KtB = pool + 8192;
    u16* VtA = pool + 16384;
    u16* VtB = pool + 24576;

    const u16* qrow = qb + ((size_t)h * 2048 + qlo + lq) * 64 + hi * 8;
    bf16x8 qf[4];
#pragma unroll
    for (int dk = 0; dk < 4; ++dk) qf[dk] = *(const bf16x8*)(qrow + dk * 16);

    f32x16 oa = {}, ob = {};
    float lsum = 0.f;

    int kstart = qlo_blk - 511; if (kstart < 0) kstart = 0;
    int ktA = kstart >> 7;
    int ktB = qlo_blk >> 7;
    const u16* kb_h = kb + (size_t)kv * 2048 * 64;
    const u16* vt_h = vt + (size_t)kv * 64 * 2048;

    auto stage = [&](u16* Kbuf, u16* Vbuf, int kt) {
        int k0 = kt << 7;
#pragma unroll
        for (int n = 0; n < 4; ++n) {
            int c = t + n * 256;
            int kr = c >> 3, kc = c & 7;
            gld_lds16(kb_h + (size_t)(k0 + kr) * 64 + ((kc ^ (kr & 7)) << 3),
                      Kbuf + c * 8);
            int vr = c >> 4, vc = c & 15;
            gld_lds16(vt_h + (size_t)vr * 2048 + k0 + ((vc ^ (vr & 15)) << 3),
                      Vbuf + c * 8);
        }
    };

    u16 *Kc = KtA, *Kn = KtB, *Vc = VtA, *Vn = VtB;
    stage(Kc, Vc, ktA);
    for (int kt = ktA; kt <= ktB; ++kt) {
        if (kt < ktB) {
            stage(Kn, Vn, kt + 1);
            asm volatile("s_waitcnt vmcnt(8)" ::: "memory");
        } else {
            asm volatile("s_waitcnt vmcnt(0)" ::: "memory");
        }
        asm volatile("s_barrier" ::: "memory");

        int k0 = kt << 7;
        int vswz = lq & 15;
#pragma unroll
        for (int pp = 0; pp < 2; ++pp) {
            int g0 = pp * 2, g1 = pp * 2 + 1;
            int k00 = k0 + g0 * 32, k01 = k0 + g1 * 32;
            bool act0 = (k00 <= qlo + 31) && (k00 + 31 >= qlo - 511);
            bool act1 = (k01 <= qlo + 31) && (k01 + 31 >= qlo - 511);
            if (!(act0 || act1)) continue;

            int kr0 = g0 * 32 + lq, kr1 = g1 * 32 + lq;
            int sz0 = kr0 & 7, sz1 = kr1 & 7;
            bf16x8 ka0 = *(const bf16x8*)&Kc[kr0 * 64 + (((0 + hi) ^ sz0) << 3)];
            bf16x8 ka1 = *(const bf16x8*)&Kc[kr0 * 64 + (((2 + hi) ^ sz0) << 3)];
            bf16x8 ka2 = *(const bf16x8*)&Kc[kr0 * 64 + (((4 + hi) ^ sz0) << 3)];
            bf16x8 ka3 = *(const bf16x8*)&Kc[kr0 * 64 + (((6 + hi) ^ sz0) << 3)];
            bf16x8 kb0 = *(const bf16x8*)&Kc[kr1 * 64 + (((0 + hi) ^ sz1) << 3)];
            bf16x8 kb1 = *(const bf16x8*)&Kc[kr1 * 64 + (((2 + hi) ^ sz1) << 3)];
            bf16x8 kb2 = *(const bf16x8*)&Kc[kr1 * 64 + (((4 + hi) ^ sz1) << 3)];
            bf16x8 kb3 = *(const bf16x8*)&Kc[kr1 * 64 + (((6 + hi) ^ sz1) << 3)];
            asm volatile("s_waitcnt lgkmcnt(0)" ::: "memory");
            __builtin_amdgcn_sched_barrier(0);

            __builtin_amdgcn_s_setprio(1);
            f32x16 s0 = {}, s1 = {};
            s0 = MFMA32(ka0, qf[0], s0);  s1 = MFMA32(kb0, qf[0], s1);
            s0 = MFMA32(ka1, qf[1], s0);  s1 = MFMA32(kb1, qf[1], s1);
            s0 = MFMA32(ka2, qf[2], s0);  s1 = MFMA32(kb2, qf[2], s1);
            s0 = MFMA32(ka3, qf[3], s0);  s1 = MFMA32(kb3, qf[3], s1);
            __builtin_amdgcn_s_setprio(0);

            bf16x8 va[2][2], vbl[2][2];
#pragma unroll
            for (int vi = 0; vi < 2; ++vi) {
                int c0 = ((g0 * 4 + vi * 2 + hi) ^ vswz) << 3;
                int c1 = ((g1 * 4 + vi * 2 + hi) ^ vswz) << 3;
                va[0][vi]  = *(const bf16x8*)&Vc[lq * 128 + c0];
                vbl[0][vi] = *(const bf16x8*)&Vc[(lq + 32) * 128 + c0];
                va[1][vi]  = *(const bf16x8*)&Vc[lq * 128 + c1];
                vbl[1][vi] = *(const bf16x8*)&Vc[(lq + 32) * 128 + c1];
            }

            int q = qlo + lq;
            bool edge0 = (k00 + 31 > qlo) || (qlo + 31 - k00 >= 512);
            if (edge0) {
#pragma unroll
                for (int r = 0; r < 16; ++r) {
                    int k = k00 + (r & 3) + 8 * (r >> 2) + 4 * hi;
                    if (!((unsigned)(q - k) < 512u)) s0[r] = -1e30f;
                }
            }
            bool edge1 = (k01 + 31 > qlo) || (qlo + 31 - k01 >= 512);
            if (edge1) {
#pragma unroll
                for (int r = 0; r < 16; ++r) {
                    int k = k01 + (r & 3) + 8 * (r >> 2) + 4 * hi;
                    if (!((unsigned)(q - k) < 512u)) s1[r] = -1e30f;
                }
            }

            float p0[16], p1[16];
#pragma unroll
            for (int r = 0; r < 16; ++r) {
                p0[r] = exp2f(s0[r]);
                p1[r] = exp2f(s1[r]);
                lsum += p0[r] + p1[r];
            }

            u32 a0 = cvtpk(p0[0], p0[1]),   a1 = cvtpk(p0[2], p0[3]);
            u32 a2 = cvtpk(p0[4], p0[5]),   a3 = cvtpk(p0[6], p0[7]);
            u32 a4 = cvtpk(p0[8], p0[9]),   a5 = cvtpk(p0[10], p0[11]);
            u32 a6 = cvtpk(p0[12], p0[13]), a7 = cvtpk(p0[14], p0[15]);
            u32 c0 = cvtpk(p1[0], p1[1]),   c1 = cvtpk(p1[2], p1[3]);
            u32 c2 = cvtpk(p1[4], p1[5]),   c3 = cvtpk(p1[6], p1[7]);
            u32 c4 = cvtpk(p1[8], p1[9]),   c5 = cvtpk(p1[10], p1[11]);
            u32 c6 = cvtpk(p1[12], p1[13]), c7 = cvtpk(p1[14], p1[15]);
            u32x2 ra02 = __builtin_amdgcn_permlane32_swap(a0, a2, false, false);
            u32x2 ra13 = __builtin_amdgcn_permlane32_swap(a1, a3, false, false);
            u32x2 ra46 = __builtin_amdgcn_permlane32_swap(a4, a6, false, false);
            u32x2 ra57 = __builtin_amdgcn_permlane32_swap(a5, a7, false, false);
            u32x2 rc02 = __builtin_amdgcn_permlane32_swap(c0, c2, false, false);
            u32x2 rc13 = __builtin_amdgcn_permlane32_swap(c1, c3, false, false);
            u32x2 rc46 = __builtin_amdgcn_permlane32_swap(c4, c6, false, false);
            u32x2 rc57 = __builtin_amdgcn_permlane32_swap(c5, c7, false, false);
            bf16x8 b0g0, b1g0, b0g1, b1g1;
            {
                u32* bp = (u32*)&b0g0;
                bp[0] = ra02[0]; bp[1] = ra13[0]; bp[2] = ra02[1]; bp[3] = ra13[1];
                u32* bq = (u32*)&b1g0;
                bq[0] = ra46[0]; bq[1] = ra57[0]; bq[2] = ra46[1]; bq[3] = ra57[1];
                u32* cp = (u32*)&b0g1;
                cp[0] = rc02[0]; cp[1] = rc13[0]; cp[2] = rc02[1]; cp[3] = rc13[1];
                u32* cq = (u32*)&b1g1;
                cq[0] = rc46[0]; cq[1] = rc57[0]; cq[2] = rc46[1]; cq[3] = rc57[1];
            }

            __builtin_amdgcn_s_setprio(1);
            oa = MFMA32(va[0][0], b0g0, oa);  ob = MFMA32(vbl[0][0], b0g0, ob);
            oa = MFMA32(va[0][1], b1g0, oa);  ob = MFMA32(vbl[0][1], b1g0, ob);
            oa = MFMA32(va[1][0], b0g1, oa);  ob = MFMA32(vbl[1][0], b0g1, ob);
            oa = MFMA32(va[1][1], b1g1, oa);  ob = MFMA32(vbl[1][1], b1g1, ob);
            __builtin_amdgcn_s_setprio(0);
        }
        asm volatile("s_barrier" ::: "memory");
        u16* tk = Kc; Kc = Kn; Kn = tk;
        u16* tv = Vc; Vc = Vn; Vn = tv;
    }

    u16* smw = pool + w * (32 * 66);
    lsum += __shfl_xor(lsum, 32);
    float inv = 1.0f / lsum;
#pragma unroll
    for (int rp = 0; rp < 8; ++rp) {
        int r = rp * 2;
        int d = (r & 3) + 8 * (r >> 2) + 4 * hi;
        *(u32*)&smw[lq * 66 + d]      = cvtpk(oa[r] * inv, oa[r + 1] * inv);
        *(u32*)&smw[lq * 66 + d + 32] = cvtpk(ob[r] * inv, ob[r + 1] * inv);
    }
    asm volatile("s_waitcnt lgkmcnt(0)" ::: "memory");
    int qr = l >> 1, dbase = (l & 1) * 32;
    size_t orow = (size_t)(qlo + qr) * 2048 + h * 64 + dbase;
#pragma unroll
    for (int c2 = 0; c2 < 8; ++c2) {
        u32 w0 = *(const u32*)&smw[qr * 66 + dbase + c2 * 4];
        u32 w1 = *(const u32*)&smw[qr * 66 + dbase + c2 * 4 + 2];
        u32x2 val = { w0, w1 };
        *(u32x2*)(ab + orow + c2 * 4) = val;
    }
}

// ---------------- launch ----------------
extern "C" void kernel_launch(void* const* d_in, const int* in_sizes, int n_in,
                              void* d_out, int out_size, void* d_ws, size_t ws_size,
                              hipStream_t stream) {
    const float* x     = (const float*)d_in[0];
    const float* w_qkv = (const float*)d_in[1];
    const float* w_out = (const float*)d_in[2];
    const float* qw    = (const float*)d_in[3];
    const float* kw    = (const float*)d_in[4];
    float* out = (float*)d_out;

    char* ws = (char*)d_ws;
    u16*   x_b    = (u16*)(ws);               // 8 MB
    u16*   wB     = (u16*)(ws + 8388608);     // 12.6 MB (w_qkv)
    u16*   q_b    = (u16*)(ws);               // overlays x_b after gemm1
    u16*   k_b    = (u16*)(ws + 8388608);     // 2 MB, overlays wB
    u16*   v_b    = (u16*)(ws + 10485760);    // 2 MB
    u16*   v_t    = (u16*)(ws + 12582912);    // 2 MB
    u16*   P0     = (u16*)(ws + 20971520);    // gemm1 bf16 partials: 2 x 12.58 MB
    u16*   O0     = (u16*)(ws + 20971520);    // gemm2 bf16 partials (reuse region)
    u16*   O1     = (u16*)(ws + 29360128);    // 8.4 MB each
    u16*   attn_b = (u16*)(ws + 54525952);    // 8 MB, ends 62914560
    u16*   wB2    = (u16*)(ws + 62914560);    // 8 MB (w_out bf16)

    cvt2_bf16<<<2048, 256, 0, stream>>>(x, x_b, 2048 * 2048 / 4,
                                        w_qkv, wB, 3072 * 2048 / 4);
    gemm_bt<2, 8, 3, 4><<<dim3(192, 2), 512, 0, stream>>>(
        x_b, wB, P0, 2048, 3072, 2048);
    qkv_post<<<2048, 256, 0, stream>>>(P0, P0 + (size_t)2048 * 3072, qw, kw,
                                       q_b, k_b, v_b);
    transpose_v<<<dim3(8, 8), 256, 0, stream>>>(v_b, v_t);
    attn_fa10<<<640, 256, 0, stream>>>(q_b, k_b, v_t, attn_b, w_out, wB2);
    gemm_bt<2, 4, 4, 2><<<dim3(128, 2), 512, 0, stream>>>(
        attn_b, wB2, O0, 2048, 2048, 2048);
    reduce_add_bf<<<1024, 256, 0, stream>>>((const u16x8*)O0, (const u16x8*)O1,
                                            (float4*)out, 2048 * 2048 / 8);
}

// Round 21
// 126.763 us; speedup vs baseline: 1.0473x; 1.0009x over previous
//
#include <hip/hip_runtime.h>

typedef unsigned short u16;
typedef unsigned int u32;
typedef __bf16 bf16x8 __attribute__((ext_vector_type(8)));
typedef float f32x4 __attribute__((ext_vector_type(4)));
typedef float f32x16 __attribute__((ext_vector_type(16)));
typedef u16 u16x8 __attribute__((ext_vector_type(8)));
typedef u32 u32x2 __attribute__((ext_vector_type(2)));
typedef u32 u32x4 __attribute__((ext_vector_type(4)));

#define MFMA16(a, b, c) __builtin_amdgcn_mfma_f32_16x16x32_bf16((a), (b), (c), 0, 0, 0)
#define MFMA32(a, b, c) __builtin_amdgcn_mfma_f32_32x32x16_bf16((a), (b), (c), 0, 0, 0)

__device__ __forceinline__ u16 f2bf(float f) {
    unsigned int u = __float_as_uint(f);
    u = (u + 0x7FFF + ((u >> 16) & 1)) >> 16;
    return (u16)u;
}

__device__ __forceinline__ float bf2f(u16 v) {
    return __uint_as_float(((u32)v) << 16);
}

__device__ __forceinline__ u32 cvtpk(float a, float b) {
    u32 d;
    asm("v_cvt_pk_bf16_f32 %0, %1, %2" : "=v"(d) : "v"(a), "v"(b));
    return d;
}

__device__ __forceinline__ void gld_lds16(const u16* g, u16* l) {
    __builtin_amdgcn_global_load_lds(
        (const __attribute__((address_space(1))) unsigned int*)g,
        (__attribute__((address_space(3))) unsigned int*)l, 16, 0, 0);
}

// ---------------- fp32 -> bf16 cast, two tensors in one dispatch ----------------
__global__ __launch_bounds__(256) void cvt2_bf16(const float* __restrict__ in1,
                                                 u16* __restrict__ out1, int n41,
                                                 const float* __restrict__ in2,
                                                 u16* __restrict__ out2, int n42) {
    int idx = blockIdx.x * blockDim.x + threadIdx.x;
    int stride = gridDim.x * blockDim.x;
    for (int i = idx; i < n41; i += stride) {
        float4 v = reinterpret_cast<const float4*>(in1)[i];
        ushort4 o;
        o.x = f2bf(v.x); o.y = f2bf(v.y); o.z = f2bf(v.z); o.w = f2bf(v.w);
        reinterpret_cast<ushort4*>(out1)[i] = o;
    }
    for (int i = idx; i < n42; i += stride) {
        float4 v = reinterpret_cast<const float4*>(in2)[i];
        ushort4 o;
        o.x = f2bf(v.x); o.y = f2bf(v.y); o.z = f2bf(v.z); o.w = f2bf(v.w);
        reinterpret_cast<ushort4*>(out2)[i] = o;
    }
}

// ---------------- bf16 partial-sum reduce: out_f32 = a_bf16 + b_bf16 ----------------
__global__ __launch_bounds__(256) void reduce_add_bf(const u16x8* __restrict__ a,
                                                     const u16x8* __restrict__ b,
                                                     float4* __restrict__ o, int n8) {
    int idx = blockIdx.x * blockDim.x + threadIdx.x;
    int stride = gridDim.x * blockDim.x;
    for (int i = idx; i < n8; i += stride) {
        u16x8 va = a[i], vb = b[i];
        float4 o0, o1;
        o0.x = bf2f(va[0]) + bf2f(vb[0]);
        o0.y = bf2f(va[1]) + bf2f(vb[1]);
        o0.z = bf2f(va[2]) + bf2f(vb[2]);
        o0.w = bf2f(va[3]) + bf2f(vb[3]);
        o1.x = bf2f(va[4]) + bf2f(vb[4]);
        o1.y = bf2f(va[5]) + bf2f(vb[5]);
        o1.z = bf2f(va[6]) + bf2f(vb[6]);
        o1.w = bf2f(va[7]) + bf2f(vb[7]);
        o[i * 2] = o0;
        o[i * 2 + 1] = o1;
    }
}

// ---- bf16 GEMM: 128x256 tile, 8 waves, depth-3 pipeline, T2 swizzle, XCD rects ----
template <int SPLITK, int RM, int RN, int XN>
__global__ __launch_bounds__(512) void gemm_bt(const u16* __restrict__ A,
                                               const u16* __restrict__ B,
                                               u16* __restrict__ C,
                                               int M, int N, int K) {
    __shared__ __align__(16) u16 As[3][128 * 32];
    __shared__ __align__(16) u16 Bs[3][256 * 32];

    int bid = blockIdx.x;
    int xcd = bid & 7;
    int r = bid >> 3;
    int tm = (xcd / XN) * RM + (r / RN);
    int tn = (xcd % XN) * RN + (r % RN);
    int m0 = tm << 7, n0 = tn << 8;

    int Ks = K / SPLITK;
    int kbase = blockIdx.y * Ks;

    int t = threadIdx.x;
    int w = t >> 6, l = t & 63, lrow = l & 15, lhi = l >> 4;
    int wr = w >> 2, wc = w & 3;

    int rowA = t >> 2;
    int col0 = (((t & 3) ^ ((t >> 3) & 3)) << 3);

    const u16* Ag = A + (size_t)m0 * K + kbase;
    const u16* Bg = B + (size_t)n0 * K + kbase;

    auto stage = [&](int sbuf, int kt) {
        int k0 = kt << 5;
        gld_lds16(Ag + (size_t)rowA * K + k0 + col0, &As[sbuf][t * 8]);
        gld_lds16(Bg + (size_t)rowA * K + k0 + col0, &Bs[sbuf][t * 8]);
        gld_lds16(Bg + (size_t)(rowA + 128) * K + k0 + col0, &Bs[sbuf][t * 8 + 4096]);
    };

    f32x4 acc[4][4] = {};
    int NT = Ks >> 5;
    stage(0, 0); stage(1, 1); stage(2, 2);
    asm volatile("s_waitcnt vmcnt(6)" ::: "memory");
    asm volatile("s_barrier" ::: "memory");
    int cur = 0;
    for (int kt = 0; kt < NT; ++kt) {
        bf16x8 af[4], bfr[4];
#pragma unroll
        for (int i = 0; i < 4; ++i) {
            int row = wr * 64 + i * 16 + lrow;
            af[i] = *(const bf16x8*)&As[cur][row * 32 + ((lhi ^ ((row >> 1) & 3)) << 3)];
        }
#pragma unroll
        for (int j = 0; j < 4; ++j) {
            int row = wc * 64 + j * 16 + lrow;
            bfr[j] = *(const bf16x8*)&Bs[cur][row * 32 + ((lhi ^ ((row >> 1) & 3)) << 3)];
        }
        asm volatile("s_waitcnt lgkmcnt(0)" ::: "memory");
        __builtin_amdgcn_sched_barrier(0);
        asm volatile("s_barrier" ::: "memory");
        if (kt + 3 < NT) stage(cur, kt + 3);
        __builtin_amdgcn_s_setprio(1);
#pragma unroll
        for (int i = 0; i < 4; ++i)
#pragma unroll
            for (int j = 0; j < 4; ++j)
                acc[i][j] = MFMA16(af[i], bfr[j], acc[i][j]);
        __builtin_amdgcn_s_setprio(0);
        if (kt + 1 < NT) {
            if (kt + 3 < NT)      asm volatile("s_waitcnt vmcnt(6)" ::: "memory");
            else if (kt + 2 < NT) asm volatile("s_waitcnt vmcnt(3)" ::: "memory");
            else                  asm volatile("s_waitcnt vmcnt(0)" ::: "memory");
            asm volatile("s_barrier" ::: "memory");
        }
        cur = (cur == 2) ? 0 : cur + 1;
    }
#pragma unroll
    for (int i = 0; i < 4; ++i) {
#pragma unroll
        for (int j = 0; j < 4; ++j) {
            int crow = m0 + wr * 64 + i * 16 + lhi * 4;
            int ccol = n0 + wc * 64 + j * 16 + lrow;
            u16* cp = C + (size_t)blockIdx.y * ((size_t)M * N) + (size_t)crow * N + ccol;
#pragma unroll
            for (int r2 = 0; r2 < 4; ++r2) cp[(size_t)r2 * N] = f2bf(acc[i][j][r2]);
        }
    }
}

// ---- qkv post: bf16 partial-add + RMSNorm + RoPE + cast + head-major ------
__global__ __launch_bounds__(256) void qkv_post(const u16* __restrict__ qkv0,
                                                const u16* __restrict__ qkv1,
                                                const float* __restrict__ qw,
                                                const float* __restrict__ kw,
                                                u16* __restrict__ qb,
                                                u16* __restrict__ kb,
                                                u16* __restrict__ vb) {
    const float C = 0.18033688011112042f;  // 0.125 * log2(e)
    int s = blockIdx.x;
    int t = threadIdx.x, w = t >> 6, lane = t & 63;
    const u16* row0 = qkv0 + (size_t)s * 3072;
    const u16* row1 = qkv1 + (size_t)s * 3072;
    int d2 = lane & 31;
    float inv = exp2f(-(float)d2 * (13.287712379549449f / 32.0f));
    float ang = (float)s * inv;
    float cs = cosf(ang), sn = sinf(ang);
    for (int h = w; h < 48; h += 4) {
        float v = bf2f(row0[h * 64 + lane]) + bf2f(row1[h * 64 + lane]);
        if (h < 40) {
            float ss = v * v;
#pragma unroll
            for (int m = 32; m; m >>= 1) ss += __shfl_xor(ss, m);
            float rms = rsqrtf(ss * (1.0f / 64.0f) + 1e-6f);
            float wgt = (h < 32) ? qw[lane] : kw[lane];
            v = v * rms * wgt;
            float part = __shfl_xor(v, 32);
            float rot = (lane < 32) ? -part : part;
            v = v * cs + rot * sn;
            if (h < 32)
                qb[((size_t)h * 2048 + s) * 64 + lane] = f2bf(v * C);
            else
                kb[((size_t)(h - 32) * 2048 + s) * 64 + lane] = f2bf(v);
        } else {
            vb[((size_t)(h - 40) * 2048 + s) * 64 + lane] = f2bf(v);
        }
    }
}

// ---------------- V transpose: vb[kv][s][d] -> vt[kv][d][s] ----------------
__global__ __launch_bounds__(256) void transpose_v(const u16* __restrict__ vb,
                                                   u16* __restrict__ vt) {
    int kv = blockIdx.y;
    int s0 = blockIdx.x * 256;
    __shared__ __align__(16) u16 tile[64][256];
    int t = threadIdx.x;
    int sl = t >> 3;
    int d0 = (t & 7) * 8;
#pragma unroll
    for (int j = 0; j < 8; ++j) {
        int s = sl + j * 32;
        u16x8 v = *(const u16x8*)(vb + ((size_t)kv * 2048 + s0 + s) * 64 + d0);
#pragma unroll
        for (int e = 0; e < 8; ++e) tile[d0 + e][s] = v[e];
    }
    __syncthreads();
    int d = t >> 2;
    int so = (t & 3) * 64;
#pragma unroll
    for (int j = 0; j < 8; ++j) {
        int s_local = so + j * 8;
        *(u16x8*)(vt + ((size_t)kv * 64 + d) * 2048 + s0 + s_local) =
            *(const u16x8*)&tile[d][s_local];
    }
}

// ---- flash attention v11: KVBLK=128, pair-batched, setprio; w_out cast folded
// INTO each block's prologue (overlaps attn staging; no serialized tail blocks).
__global__ __launch_bounds__(256) void attn_fa11(const u16* __restrict__ qb,
                                                 const u16* __restrict__ kb,
                                                 const u16* __restrict__ vt,
                                                 u16* __restrict__ ab,
                                                 const float* __restrict__ wout,
                                                 u16* __restrict__ wb2) {
    int bid = blockIdx.x;
    // cast this block's 1/512 slice of w_out (8 float4 per thread, contiguous)
    {
        int base = bid * 2048 + threadIdx.x;
#pragma unroll
        for (int k2 = 0; k2 < 8; ++k2) {
            int i = base + k2 * 256;
            float4 v = reinterpret_cast<const float4*>(wout)[i];
            ushort4 o;
            o.x = f2bf(v.x); o.y = f2bf(v.y); o.z = f2bf(v.z); o.w = f2bf(v.w);
            reinterpret_cast<ushort4*>(wb2)[i] = o;
        }
    }
    int qt = bid & 15, h = bid >> 4, kv = h >> 2;
    int t = threadIdx.x, w = t >> 6, l = t & 63;
    int lq = l & 31, hi = l >> 5;
    int qlo_blk = qt * 128;
    int qlo = qlo_blk + w * 32;

    __shared__ __align__(16) u16 pool[32768];
    u16* KtA = pool;
    u16* KtB = pool + 8192;
    u16* VtA = pool + 16384;
    u16* VtB = pool + 24576;

    const u16* qrow = qb + ((size_t)h * 2048 + qlo + lq) * 64 + hi * 8;
    bf16x8 qf[4];
#pragma unroll
    for (int dk = 0; dk < 4; ++dk) qf[dk] = *(const bf16x8*)(qrow + dk * 16);

    f32x16 oa = {}, ob = {};
    float lsum = 0.f;

    int kstart = qlo_blk - 511; if (kstart < 0) kstart = 0;
    int ktA = kstart >> 7;
    int ktB = qlo_blk >> 7;
    const u16* kb_h = kb + (size_t)kv * 2048 * 64;
    const u16* vt_h = vt + (size_t)kv * 64 * 2048;

    auto stage = [&](u16* Kbuf, u16* Vbuf, int kt) {
        int k0 = kt << 7;
#pragma unroll
        for (int n = 0; n < 4; ++n) {
            int c = t + n * 256;
            int kr = c >> 3, kc = c & 7;
            gld_lds16(kb_h + (size_t)(k0 + kr) * 64 + ((kc ^ (kr & 7)) << 3),
                      Kbuf + c * 8);
            int vr = c >> 4, vc = c & 15;
            gld_lds16(vt_h + (size_t)vr * 2048 + k0 + ((vc ^ (vr & 15)) << 3),
                      Vbuf + c * 8);
        }
    };

    u16 *Kc = KtA, *Kn = KtB, *Vc = VtA, *Vn = VtB;
    stage(Kc, Vc, ktA);
    for (int kt = ktA; kt <= ktB; ++kt) {
        if (kt < ktB) {
            stage(Kn, Vn, kt + 1);
            asm volatile("s_waitcnt vmcnt(8)" ::: "memory");
        } else {
            asm volatile("s_waitcnt vmcnt(0)" ::: "memory");
        }
        asm volatile("s_barrier" ::: "memory");

        int k0 = kt << 7;
        int vswz = lq & 15;
#pragma unroll
        for (int pp = 0; pp < 2; ++pp) {
            int g0 = pp * 2, g1 = pp * 2 + 1;
            int k00 = k0 + g0 * 32, k01 = k0 + g1 * 32;
            bool act0 = (k00 <= qlo + 31) && (k00 + 31 >= qlo - 511);
            bool act1 = (k01 <= qlo + 31) && (k01 + 31 >= qlo - 511);
            if (!(act0 || act1)) continue;

            int kr0 = g0 * 32 + lq, kr1 = g1 * 32 + lq;
            int sz0 = kr0 & 7, sz1 = kr1 & 7;
            bf16x8 ka0 = *(const bf16x8*)&Kc[kr0 * 64 + (((0 + hi) ^ sz0) << 3)];
            bf16x8 ka1 = *(const bf16x8*)&Kc[kr0 * 64 + (((2 + hi) ^ sz0) << 3)];
            bf16x8 ka2 = *(const bf16x8*)&Kc[kr0 * 64 + (((4 + hi) ^ sz0) << 3)];
            bf16x8 ka3 = *(const bf16x8*)&Kc[kr0 * 64 + (((6 + hi) ^ sz0) << 3)];
            bf16x8 kb0 = *(const bf16x8*)&Kc[kr1 * 64 + (((0 + hi) ^ sz1) << 3)];
            bf16x8 kb1 = *(const bf16x8*)&Kc[kr1 * 64 + (((2 + hi) ^ sz1) << 3)];
            bf16x8 kb2 = *(const bf16x8*)&Kc[kr1 * 64 + (((4 + hi) ^ sz1) << 3)];
            bf16x8 kb3 = *(const bf16x8*)&Kc[kr1 * 64 + (((6 + hi) ^ sz1) << 3)];
            asm volatile("s_waitcnt lgkmcnt(0)" ::: "memory");
            __builtin_amdgcn_sched_barrier(0);

            __builtin_amdgcn_s_setprio(1);
            f32x16 s0 = {}, s1 = {};
            s0 = MFMA32(ka0, qf[0], s0);  s1 = MFMA32(kb0, qf[0], s1);
            s0 = MFMA32(ka1, qf[1], s0);  s1 = MFMA32(kb1, qf[1], s1);
            s0 = MFMA32(ka2, qf[2], s0);  s1 = MFMA32(kb2, qf[2], s1);
            s0 = MFMA32(ka3, qf[3], s0);  s1 = MFMA32(kb3, qf[3], s1);
            __builtin_amdgcn_s_setprio(0);

            bf16x8 va[2][2], vbl[2][2];
#pragma unroll
            for (int vi = 0; vi < 2; ++vi) {
                int c0 = ((g0 * 4 + vi * 2 + hi) ^ vswz) << 3;
                int c1 = ((g1 * 4 + vi * 2 + hi) ^ vswz) << 3;
                va[0][vi]  = *(const bf16x8*)&Vc[lq * 128 + c0];
                vbl[0][vi] = *(const bf16x8*)&Vc[(lq + 32) * 128 + c0];
                va[1][vi]  = *(const bf16x8*)&Vc[lq * 128 + c1];
                vbl[1][vi] = *(const bf16x8*)&Vc[(lq + 32) * 128 + c1];
            }

            int q = qlo + lq;
            bool edge0 = (k00 + 31 > qlo) || (qlo + 31 - k00 >= 512);
            if (edge0) {
#pragma unroll
                for (int r = 0; r < 16; ++r) {
                    int k = k00 + (r & 3) + 8 * (r >> 2) + 4 * hi;
                    if (!((unsigned)(q - k) < 512u)) s0[r] = -1e30f;
                }
            }
            bool edge1 = (k01 + 31 > qlo) || (qlo + 31 - k01 >= 512);
            if (edge1) {
#pragma unroll
                for (int r = 0; r < 16; ++r) {
                    int k = k01 + (r & 3) + 8 * (r >> 2) + 4 * hi;
                    if (!((unsigned)(q - k) < 512u)) s1[r] = -1e30f;
                }
            }

            float p0[16], p1[16];
#pragma unroll
            for (int r = 0; r < 16; ++r) {
                p0[r] = exp2f(s0[r]);
                p1[r] = exp2f(s1[r]);
                lsum += p0[r] + p1[r];
            }

            u32 a0 = cvtpk(p0[0], p0[1]),   a1 = cvtpk(p0[2], p0[3]);
            u32 a2 = cvtpk(p0[4], p0[5]),   a3 = cvtpk(p0[6], p0[7]);
            u32 a4 = cvtpk(p0[8], p0[9]),   a5 = cvtpk(p0[10], p0[11]);
            u32 a6 = cvtpk(p0[12], p0[13]), a7 = cvtpk(p0[14], p0[15]);
            u32 c0 = cvtpk(p1[0], p1[1]),   c1 = cvtpk(p1[2], p1[3]);
            u32 c2 = cvtpk(p1[4], p1[5]),   c3 = cvtpk(p1[6], p1[7]);
            u32 c4 = cvtpk(p1[8], p1[9]),   c5 = cvtpk(p1[10], p1[11]);
            u32 c6 = cvtpk(p1[12], p1[13]), c7 = cvtpk(p1[14], p1[15]);
            u32x2 ra02 = __builtin_amdgcn_permlane32_swap(a0, a2, false, false);
            u32x2 ra13 = __builtin_amdgcn_permlane32_swap(a1, a3, false, false);
            u32x2 ra46 = __builtin_amdgcn_permlane32_swap(a4, a6, false, false);
            u32x2 ra57 = __builtin_amdgcn_permlane32_swap(a5, a7, false, false);
            u32x2 rc02 = __builtin_amdgcn_permlane32_swap(c0, c2, false, false);
            u32x2 rc13 = __builtin_amdgcn_permlane32_swap(c1, c3, false, false);
            u32x2 rc46 = __builtin_amdgcn_permlane32_swap(c4, c6, false, false);
            u32x2 rc57 = __builtin_amdgcn_permlane32_swap(c5, c7, false, false);
            bf16x8 b0g0, b1g0, b0g1, b1g1;
            {
                u32* bp = (u32*)&b0g0;
                bp[0] = ra02[0]; bp[1] = ra13[0]; bp[2] = ra02[1]; bp[3] = ra13[1];
                u32* bq = (u32*)&b1g0;
                bq[0] = ra46[0]; bq[1] = ra57[0]; bq[2] = ra46[1]; bq[3] = ra57[1];
                u32* cp = (u32*)&b0g1;
                cp[0] = rc02[0]; cp[1] = rc13[0]; cp[2] = rc02[1]; cp[3] = rc13[1];
                u32* cq = (u32*)&b1g1;
                cq[0] = rc46[0]; cq[1] = rc57[0]; cq[2] = rc46[1]; cq[3] = rc57[1];
            }

            __builtin_amdgcn_s_setprio(1);
            oa = MFMA32(va[0][0], b0g0, oa);  ob = MFMA32(vbl[0][0], b0g0, ob);
            oa = MFMA32(va[0][1], b1g0, oa);  ob = MFMA32(vbl[0][1], b1g0, ob);
            oa = MFMA32(va[1][0], b0g1, oa);  ob = MFMA32(vbl[1][0], b0g1, ob);
            oa = MFMA32(va[1][1], b1g1, oa);  ob = MFMA32(vbl[1][1], b1g1, ob);
            __builtin_amdgcn_s_setprio(0);
        }
        asm volatile("s_barrier" ::: "memory");
        u16* tk = Kc; Kc = Kn; Kn = tk;
        u16* tv = Vc; Vc = Vn; Vn = tv;
    }

    u16* smw = pool + w * (32 * 66);
    lsum += __shfl_xor(lsum, 32);
    float inv = 1.0f / lsum;
#pragma unroll
    for (int rp = 0; rp < 8; ++rp) {
        int r = rp * 2;
        int d = (r & 3) + 8 * (r >> 2) + 4 * hi;
        *(u32*)&smw[lq * 66 + d]      = cvtpk(oa[r] * inv, oa[r + 1] * inv);
        *(u32*)&smw[lq * 66 + d + 32] = cvtpk(ob[r] * inv, ob[r + 1] * inv);
    }
    asm volatile("s_waitcnt lgkmcnt(0)" ::: "memory");
    int qr = l >> 1, dbase = (l & 1) * 32;
    size_t orow = (size_t)(qlo + qr) * 2048 + h * 64 + dbase;
#pragma unroll
    for (int c2 = 0; c2 < 8; ++c2) {
        u32 w0 = *(const u32*)&smw[qr * 66 + dbase + c2 * 4];
        u32 w1 = *(const u32*)&smw[qr * 66 + dbase + c2 * 4 + 2];
        u32x2 val = { w0, w1 };
        *(u32x2*)(ab + orow + c2 * 4) = val;
    }
}

// ---------------- launch ----------------
extern "C" void kernel_launch(void* const* d_in, const int* in_sizes, int n_in,
                              void* d_out, int out_size, void* d_ws, size_t ws_size,
                              hipStream_t stream) {
    const float* x     = (const float*)d_in[0];
    const float* w_qkv = (const float*)d_in[1];
    const float* w_out = (const float*)d_in[2];
    const float* qw    = (const float*)d_in[3];
    const float* kw    = (const float*)d_in[4];
    float* out = (float*)d_out;

    char* ws = (char*)d_ws;
    u16*   x_b    = (u16*)(ws);               // 8 MB
    u16*   wB     = (u16*)(ws + 8388608);     // 12.6 MB (w_qkv)
    u16*   q_b    = (u16*)(ws);               // overlays x_b after gemm1
    u16*   k_b    = (u16*)(ws + 8388608);     // 2 MB, overlays wB
    u16*   v_b    = (u16*)(ws + 10485760);    // 2 MB
    u16*   v_t    = (u16*)(ws + 12582912);    // 2 MB
    u16*   P0     = (u16*)(ws + 20971520);    // gemm1 bf16 partials: 2 x 12.58 MB
    u16*   O0     = (u16*)(ws + 20971520);    // gemm2 bf16 partials (reuse region)
    u16*   O1     = (u16*)(ws + 29360128);    // 8.4 MB each
    u16*   attn_b = (u16*)(ws + 54525952);    // 8 MB, ends 62914560
    u16*   wB2    = (u16*)(ws + 62914560);    // 8 MB (w_out bf16)

    cvt2_bf16<<<2048, 256, 0, stream>>>(x, x_b, 2048 * 2048 / 4,
                                        w_qkv, wB, 3072 * 2048 / 4);
    gemm_bt<2, 8, 3, 4><<<dim3(192, 2), 512, 0, stream>>>(
        x_b, wB, P0, 2048, 3072, 2048);
    qkv_post<<<2048, 256, 0, stream>>>(P0, P0 + (size_t)2048 * 3072, qw, kw,
                                       q_b, k_b, v_b);
    transpose_v<<<dim3(8, 8), 256, 0, stream>>>(v_b, v_t);
    attn_fa11<<<512, 256, 0, stream>>>(q_b, k_b, v_t, attn_b, w_out, wB2);
    gemm_bt<2, 4, 4, 2><<<dim3(128, 2), 512, 0, stream>>>(
        attn_b, wB2, O0, 2048, 2048, 2048);
    reduce_add_bf<<<1024, 256, 0, stream>>>((const u16x8*)O0, (const u16x8*)O1,
                                            (float4*)out, 2048 * 2048 / 8);
}